// Round 8
// baseline (400.879 us; speedup 1.0000x reference)
//
#include <hip/hip_runtime.h>
#include <hip/hip_bf16.h>

static constexpr int N_NODES = 50000;
static constexpr int N_EDGE  = 1000000;
static constexpr int IN_D    = 256;
static constexpr int HID_D   = 128;
static constexpr int OUT_D   = 64;
static constexpr int R_REL   = 2;

typedef __attribute__((ext_vector_type(8))) short short8;            // 8 bf16 = 4 VGPRs
typedef __attribute__((ext_vector_type(8))) unsigned short ushort8;  // store type
typedef __attribute__((ext_vector_type(4))) float float4v;
typedef __attribute__((ext_vector_type(2))) float float2v;           // v_pk_fma_f32 pair

static __device__ __forceinline__ unsigned short f2bf(float v) {
    __hip_bfloat16 h = __float2bfloat16(v);
    return *(unsigned short*)&h;
}
static __device__ __forceinline__ float bf2f(unsigned short u) {
    union { unsigned int i; float f; } c; c.i = ((unsigned int)u) << 16; return c.f;
}
// low/high bf16 of a packed u32 -> f32 (1 VALU each: lshl / and)
static __device__ __forceinline__ float bflo(unsigned u) {
    union { unsigned i; float f; } c; c.i = u << 16; return c.f;
}
static __device__ __forceinline__ float bfhi(unsigned u) {
    union { unsigned i; float f; } c; c.i = u & 0xFFFF0000u; return c.f;
}
static __device__ __forceinline__ float u2f(unsigned u) {
    union { unsigned i; float f; } c; c.i = u; return c.f;
}
static __device__ __forceinline__ unsigned f2u(float f) {
    union { unsigned i; float f; } c; c.f = f; return c.i;
}
// accumulate 8 bf16 (one uint4) scaled by w into 4 packed f32 pairs.
// <2 x float> fma lowers to v_pk_fma_f32 on gfx90a+ — halves FMA issue count
// vs scalar fmaf (round-7 profile: aggr1 VALUBusy 72%, VALU-issue-bound).
// Bit-identical numerics (pk_fma = 2 independent IEEE f32 FMAs).
static __device__ __forceinline__ void acc8p(float w, uint4 v, float2v (&a)[4]) {
    const float2v w2 = {w, w};
    const float2v t0 = {bflo(v.x), bfhi(v.x)};
    const float2v t1 = {bflo(v.y), bfhi(v.y)};
    const float2v t2 = {bflo(v.z), bfhi(v.z)};
    const float2v t3 = {bflo(v.w), bfhi(v.w)};
    a[0] = __builtin_elementwise_fma(w2, t0, a[0]);
    a[1] = __builtin_elementwise_fma(w2, t1, a[1]);
    a[2] = __builtin_elementwise_fma(w2, t2, a[2]);
    a[3] = __builtin_elementwise_fma(w2, t3, a[3]);
}

// ---- merged weight prep: W1/W2 transpose-convert + dec weight hi/lo split ----
__global__ __launch_bounds__(256) void prep_k(
    const float* __restrict__ W1, const float* __restrict__ W2,
    const float* __restrict__ dw1, const float* __restrict__ dw2,
    unsigned short* __restrict__ Wc1t, unsigned short* __restrict__ Wc2t,
    unsigned short* __restrict__ dw1h, unsigned short* __restrict__ dw1l,
    unsigned short* __restrict__ dw2h, unsigned short* __restrict__ dw2l)
{
    int idx = blockIdx.x * 256 + threadIdx.x;
    if (idx < R_REL * HID_D * IN_D) {                       // 65536
        const int n = idx / IN_D, kk = idx % IN_D;
        const int r = n / HID_D, o = n % HID_D;
        Wc1t[(long)n * IN_D + kk] = f2bf(W1[((long)r * IN_D + kk) * HID_D + o]);
        return;
    }
    idx -= R_REL * HID_D * IN_D;
    if (idx < R_REL * OUT_D * HID_D) {                      // 16384
        const int n = idx / HID_D, kk = idx % HID_D;
        const int r = n / OUT_D, o = n % OUT_D;
        Wc2t[(long)n * HID_D + kk] = f2bf(W2[((long)r * HID_D + kk) * OUT_D + o]);
        return;
    }
    idx -= R_REL * OUT_D * HID_D;
    if (idx < HID_D * OUT_D) {                              // 8192
        const float v = dw1[idx];
        const unsigned short hi = f2bf(v);
        dw1h[idx] = hi; dw1l[idx] = f2bf(v - bf2f(hi));
        return;
    }
    idx -= HID_D * OUT_D;
    if (idx < IN_D * HID_D) {                               // 32768
        const float v = dw2[idx];
        const unsigned short hi = f2bf(v);
        dw2h[idx] = hi; dw2l[idx] = f2bf(v - bf2f(hi));
    }
}

// ---------------- bf16 MFMA GEMM: Cb[M,N] (bf16) = A[M,K] @ Bt[N,K]^T ----------
// BM=128 + spill-free register prefetch in NAMED registers (macro-assigned).
// CVT=true: A is fp32, converted to bf16 in registers during LDS commit.
template<bool CVT>
__global__ __launch_bounds__(256) void gemm_bf16_k(
    const unsigned short* __restrict__ A, const float* __restrict__ Af,
    const unsigned short* __restrict__ Bt,
    unsigned short* __restrict__ Cb, int M, int K, int Nn)
{
    constexpr int BM = 128;
    constexpr int LDK = 40;   // 80 B rows: 16B-aligned, 2-way-only bank conflicts
    __shared__ __align__(16) unsigned short As[BM * LDK];
    __shared__ __align__(16) unsigned short Bs[128 * LDK];

    const int tid = threadIdx.x;
    const int wave = tid >> 6, lane = tid & 63;
    const int wm = (wave >> 1) * 64;
    const int wn = (wave & 1) * 64;
    const int bm = blockIdx.y * BM;
    const int bn = blockIdx.x * 128;
    const int l15 = lane & 15, quad = lane >> 4;

    const int ar0 = tid >> 2,          ach0 = (tid & 3) * 8;
    const int ar1 = (tid + 256) >> 2,  ach1 = (tid & 3) * 8;   // (tid+256)&3 == tid&3
    const long ga0 = (long)min(bm + ar0, M - 1) * K + ach0;
    const long ga1 = (long)min(bm + ar1, M - 1) * K + ach1;
    const long gb0 = (long)(bn + ar0) * K + ach0;
    const long gb1 = (long)(bn + ar1) * K + ach1;

    float4 fa0, fa1, fa2, fa3;   // CVT prefetch (fp32, 2 chunks x 2 float4)
    uint4  qa0, qa1;             // bf16 prefetch
    uint4  qb0, qb1;             // B prefetch

#define GEMM_PREF(k0) do {                                                  \
    if constexpr (CVT) {                                                    \
        fa0 = *(const float4*)&Af[ga0 + (k0)];                              \
        fa1 = *(const float4*)&Af[ga0 + (k0) + 4];                          \
        fa2 = *(const float4*)&Af[ga1 + (k0)];                              \
        fa3 = *(const float4*)&Af[ga1 + (k0) + 4];                          \
    } else {                                                                \
        qa0 = *(const uint4*)&A[ga0 + (k0)];                                \
        qa1 = *(const uint4*)&A[ga1 + (k0)];                                \
    }                                                                       \
    qb0 = *(const uint4*)&Bt[gb0 + (k0)];                                   \
    qb1 = *(const uint4*)&Bt[gb1 + (k0)];                                   \
} while (0)

#define GEMM_COMMIT() do {                                                  \
    if constexpr (CVT) {                                                    \
        uint4 o0, o1;                                                       \
        o0.x = (unsigned)f2bf(fa0.x) | ((unsigned)f2bf(fa0.y) << 16);       \
        o0.y = (unsigned)f2bf(fa0.z) | ((unsigned)f2bf(fa0.w) << 16);       \
        o0.z = (unsigned)f2bf(fa1.x) | ((unsigned)f2bf(fa1.y) << 16);       \
        o0.w = (unsigned)f2bf(fa1.z) | ((unsigned)f2bf(fa1.w) << 16);       \
        o1.x = (unsigned)f2bf(fa2.x) | ((unsigned)f2bf(fa2.y) << 16);       \
        o1.y = (unsigned)f2bf(fa2.z) | ((unsigned)f2bf(fa2.w) << 16);       \
        o1.z = (unsigned)f2bf(fa3.x) | ((unsigned)f2bf(fa3.y) << 16);       \
        o1.w = (unsigned)f2bf(fa3.z) | ((unsigned)f2bf(fa3.w) << 16);       \
        *(uint4*)&As[ar0 * LDK + ach0] = o0;                                \
        *(uint4*)&As[ar1 * LDK + ach1] = o1;                                \
    } else {                                                                \
        *(uint4*)&As[ar0 * LDK + ach0] = qa0;                               \
        *(uint4*)&As[ar1 * LDK + ach1] = qa1;                               \
    }                                                                       \
    *(uint4*)&Bs[ar0 * LDK + ach0] = qb0;                                   \
    *(uint4*)&Bs[ar1 * LDK + ach1] = qb1;                                   \
} while (0)

    float4v acc[4][4];
#pragma unroll
    for (int i = 0; i < 4; ++i)
#pragma unroll
        for (int j = 0; j < 4; ++j) acc[i][j] = (float4v){0.f, 0.f, 0.f, 0.f};

    GEMM_PREF(0);
    for (int k0 = 0; k0 < K; k0 += 32) {
        GEMM_COMMIT();
        __syncthreads();
        if (k0 + 32 < K) GEMM_PREF(k0 + 32);   // in flight across MFMA phase

        short8 bfrag[4];
#pragma unroll
        for (int nt = 0; nt < 4; ++nt)
            bfrag[nt] = *(const short8*)&Bs[(wn + nt * 16 + l15) * LDK + quad * 8];
#pragma unroll
        for (int mt = 0; mt < 4; ++mt) {
            const short8 afrag = *(const short8*)&As[(wm + mt * 16 + l15) * LDK + quad * 8];
#pragma unroll
            for (int nt = 0; nt < 4; ++nt)
                acc[mt][nt] = __builtin_amdgcn_mfma_f32_16x16x32_bf16(
                    afrag, bfrag[nt], acc[mt][nt], 0, 0, 0);
        }
        __syncthreads();
    }
#undef GEMM_PREF
#undef GEMM_COMMIT

    // C/D layout: col = lane&15, row = quad*4 + reg (m89-verified)
#pragma unroll
    for (int mt = 0; mt < 4; ++mt)
#pragma unroll
        for (int nt = 0; nt < 4; ++nt) {
            const int n = bn + wn + nt * 16 + l15;
#pragma unroll
            for (int rg = 0; rg < 4; ++rg) {
                const int m = bm + wm + mt * 16 + quad * 4 + rg;
                if (m < M) Cb[(long)m * Nn + n] = f2bf(acc[mt][nt][rg]);
            }
        }
}

// -------- decoder split-bf16 MFMA GEMM: C = (Ah+Al)(Bh+Bl)^T + bias ------------
// Same spill-free named-register prefetch, 4 input streams.
template<bool SPLITOUT>
__global__ __launch_bounds__(256) void dec_gemm_k(
    const unsigned short* __restrict__ Ah, const unsigned short* __restrict__ Al,
    const unsigned short* __restrict__ Bh, const unsigned short* __restrict__ Bl,
    const float* __restrict__ bias, float* __restrict__ Cf,
    unsigned short* __restrict__ Ch, unsigned short* __restrict__ Cl,
    int M, int K, int Nn)
{
    constexpr int BM = 128;
    constexpr int LDK = 40;
    __shared__ __align__(16) unsigned short Ash[BM * LDK];
    __shared__ __align__(16) unsigned short Asl[BM * LDK];
    __shared__ __align__(16) unsigned short Bsh[128 * LDK];
    __shared__ __align__(16) unsigned short Bsl[128 * LDK];

    const int tid = threadIdx.x;
    const int wave = tid >> 6, lane = tid & 63;
    const int wm = (wave >> 1) * 64;
    const int wn = (wave & 1) * 64;
    const int bm = blockIdx.y * BM;
    const int bn = blockIdx.x * 128;
    const int l15 = lane & 15, quad = lane >> 4;

    const int ar0 = tid >> 2,          ach0 = (tid & 3) * 8;
    const int ar1 = (tid + 256) >> 2,  ach1 = (tid & 3) * 8;
    const long ga0 = (long)min(bm + ar0, M - 1) * K + ach0;
    const long ga1 = (long)min(bm + ar1, M - 1) * K + ach1;
    const long gb0 = (long)(bn + ar0) * K + ach0;
    const long gb1 = (long)(bn + ar1) * K + ach1;

    uint4 ph0, ph1, pl0, pl1;     // A hi/lo prefetch
    uint4 rh0, rh1, rl0, rl1;     // B hi/lo prefetch

#define DEC_PREF(k0) do {                                   \
    ph0 = *(const uint4*)&Ah[ga0 + (k0)];                   \
    ph1 = *(const uint4*)&Ah[ga1 + (k0)];                   \
    pl0 = *(const uint4*)&Al[ga0 + (k0)];                   \
    pl1 = *(const uint4*)&Al[ga1 + (k0)];                   \
    rh0 = *(const uint4*)&Bh[gb0 + (k0)];                   \
    rh1 = *(const uint4*)&Bh[gb1 + (k0)];                   \
    rl0 = *(const uint4*)&Bl[gb0 + (k0)];                   \
    rl1 = *(const uint4*)&Bl[gb1 + (k0)];                   \
} while (0)

#define DEC_COMMIT() do {                                   \
    *(uint4*)&Ash[ar0 * LDK + ach0] = ph0;                  \
    *(uint4*)&Ash[ar1 * LDK + ach1] = ph1;                  \
    *(uint4*)&Asl[ar0 * LDK + ach0] = pl0;                  \
    *(uint4*)&Asl[ar1 * LDK + ach1] = pl1;                  \
    *(uint4*)&Bsh[ar0 * LDK + ach0] = rh0;                  \
    *(uint4*)&Bsh[ar1 * LDK + ach1] = rh1;                  \
    *(uint4*)&Bsl[ar0 * LDK + ach0] = rl0;                  \
    *(uint4*)&Bsl[ar1 * LDK + ach1] = rl1;                  \
} while (0)

    float4v acc[4][4];
#pragma unroll
    for (int i = 0; i < 4; ++i)
#pragma unroll
        for (int j = 0; j < 4; ++j) acc[i][j] = (float4v){0.f, 0.f, 0.f, 0.f};

    DEC_PREF(0);
    for (int k0 = 0; k0 < K; k0 += 32) {
        DEC_COMMIT();
        __syncthreads();
        if (k0 + 32 < K) DEC_PREF(k0 + 32);

        short8 bh[4], bl[4];
#pragma unroll
        for (int nt = 0; nt < 4; ++nt) {
            bh[nt] = *(const short8*)&Bsh[(wn + nt * 16 + l15) * LDK + quad * 8];
            bl[nt] = *(const short8*)&Bsl[(wn + nt * 16 + l15) * LDK + quad * 8];
        }
#pragma unroll
        for (int mt = 0; mt < 4; ++mt) {
            const short8 ah = *(const short8*)&Ash[(wm + mt * 16 + l15) * LDK + quad * 8];
            const short8 al = *(const short8*)&Asl[(wm + mt * 16 + l15) * LDK + quad * 8];
#pragma unroll
            for (int nt = 0; nt < 4; ++nt) {
                acc[mt][nt] = __builtin_amdgcn_mfma_f32_16x16x32_bf16(ah, bh[nt], acc[mt][nt], 0, 0, 0);
                acc[mt][nt] = __builtin_amdgcn_mfma_f32_16x16x32_bf16(al, bh[nt], acc[mt][nt], 0, 0, 0);
                acc[mt][nt] = __builtin_amdgcn_mfma_f32_16x16x32_bf16(ah, bl[nt], acc[mt][nt], 0, 0, 0);
            }
        }
        __syncthreads();
    }
#undef DEC_PREF
#undef DEC_COMMIT

#pragma unroll
    for (int mt = 0; mt < 4; ++mt)
#pragma unroll
        for (int nt = 0; nt < 4; ++nt) {
            const int n = bn + wn + nt * 16 + l15;
            const float bv = bias[n];
#pragma unroll
            for (int rg = 0; rg < 4; ++rg) {
                const int m = bm + wm + mt * 16 + quad * 4 + rg;
                if (m >= M) continue;
                const float v = acc[mt][nt][rg] + bv;
                if (SPLITOUT) {
                    const unsigned short hi = f2bf(v);
                    Ch[(long)m * Nn + n] = hi;
                    Cl[(long)m * Nn + n] = f2bf(v - bf2f(hi));
                } else {
                    Cf[(long)m * Nn + n] = v;
                }
            }
        }
}

// ---------------- q/k dots over bf16 proj [node][R*D] --------------------------
// qd layout: interleaved [node][2] so consumers read one float2.
template<int D>
__global__ __launch_bounds__(256) void dotsB_k(
    const unsigned short* __restrict__ projb, const float* __restrict__ q,
    const float* __restrict__ k, float* __restrict__ qd, float* __restrict__ kd,
    int Nn)
{
    const int node = (int)((blockIdx.x * (long)blockDim.x + threadIdx.x) >> 6);
    const int lane = threadIdx.x & 63;
    if (node >= Nn) return;
    const unsigned short* row = projb + (long)node * (2 * D);
    float sq0, sk0, sq1, sk1;
    if (D == 128) {
        const ushort2 a = *(const ushort2*)(row + 2 * lane);
        const ushort2 b = *(const ushort2*)(row + 128 + 2 * lane);
        const float q0 = q[2 * lane], q1 = q[2 * lane + 1];
        const float c0 = k[2 * lane], c1 = k[2 * lane + 1];
        const float a0 = bf2f(a.x), a1 = bf2f(a.y);
        const float b0 = bf2f(b.x), b1 = bf2f(b.y);
        sq0 = fmaf(a0, q0, a1 * q1); sk0 = fmaf(a0, c0, a1 * c1);
        sq1 = fmaf(b0, q0, b1 * q1); sk1 = fmaf(b0, c0, b1 * c1);
    } else {
        const float a0 = bf2f(row[lane]), b0 = bf2f(row[64 + lane]);
        const float q0 = q[lane], c0 = k[lane];
        sq0 = a0 * q0; sk0 = a0 * c0;
        sq1 = b0 * q0; sk1 = b0 * c0;
    }
#pragma unroll
    for (int off = 32; off; off >>= 1) {
        sq0 += __shfl_xor(sq0, off); sk0 += __shfl_xor(sk0, off);
        sq1 += __shfl_xor(sq1, off); sk1 += __shfl_xor(sk1, off);
    }
    if (lane == 0) {
        *(float2*)&qd[2 * node] = make_float2(sq0, sq1);
        kd[node] = sk0; kd[Nn + node] = sk1;
    }
}

// ---------------- CSR build (rank/scan/place — no atomic->scatter chain) -------
// rank_k atomics go to a line-padded counter array (stride 16 ints = 64B/node).
static constexpr int CPAD = 16;   // ints per counter slot (64 B)

__global__ __launch_bounds__(256) void rank_k(
    const int* __restrict__ dstv, int* __restrict__ cntp,
    int* __restrict__ rank, int E)
{
    const int e = blockIdx.x * blockDim.x + threadIdx.x;
    if (e >= E) return;
    rank[e] = atomicAdd(&cntp[dstv[e] * CPAD], 1);
}

__global__ __launch_bounds__(256) void scan1_k(
    const int* __restrict__ cntp, int* __restrict__ excl_out,
    int* __restrict__ bsum, int n)
{
    __shared__ int s[256];
    const int t = threadIdx.x;
    const int i = blockIdx.x * 256 + t;
    const int v = (i < n) ? cntp[i * CPAD] : 0;
    s[t] = v;
    __syncthreads();
    for (int off = 1; off < 256; off <<= 1) {
        const int x = (t >= off) ? s[t - off] : 0;
        __syncthreads();
        s[t] += x;
        __syncthreads();
    }
    if (i < n) excl_out[i] = s[t] - v;
    if (t == 255) bsum[blockIdx.x] = s[255];
}

__global__ __launch_bounds__(256) void scan2_k(
    int* __restrict__ bsum, int* __restrict__ bpre, int nb)
{
    __shared__ int s[256];
    const int t = threadIdx.x;
    const int v = (t < nb) ? bsum[t] : 0;
    s[t] = v;
    __syncthreads();
    for (int off = 1; off < 256; off <<= 1) {
        const int x = (t >= off) ? s[t - off] : 0;
        __syncthreads();
        s[t] += x;
        __syncthreads();
    }
    if (t < nb) bpre[t] = s[t] - v;
}

__global__ __launch_bounds__(256) void scan3_k(
    int* __restrict__ excl, const int* __restrict__ bpre,
    int* __restrict__ offs, int n, int total)
{
    const int i = blockIdx.x * 256 + threadIdx.x;
    if (i >= n) return;
    offs[i] = excl[i] + bpre[i >> 8];
    if (i == 0) offs[n] = total;
}

// place_k: deterministic position, single 4B record write, no atomics.
// record = (etype << 16) | src   (src < 65536 since N_NODES = 50000)
__global__ __launch_bounds__(256) void place_k(
    const int* __restrict__ srcv, const int* __restrict__ dstv,
    const int* __restrict__ et, const int* __restrict__ rank,
    const int* __restrict__ offs, unsigned* __restrict__ recs, int E)
{
    const int e = blockIdx.x * blockDim.x + threadIdx.x;
    if (e >= E) return;
    const int pos = offs[dstv[e]] + rank[e];
    recs[pos] = (unsigned)((et[e] << 16) | srcv[e]);
}

// -------- layer-1 fused softmax+aggr+ELU, quarter-wave uint4 gather ------------
// Row = 128 bf16 = 256B = 16 lanes x uint4; 4 edges per load, 4 loads in flight
// covering 16 edges per burst. Accumulate path uses v_pk_fma_f32 pairs.
__global__ __launch_bounds__(256) void aggr1_k(
    const int* __restrict__ offs, const unsigned* __restrict__ recs,
    const float* __restrict__ qd, const float* __restrict__ kd,
    const unsigned short* __restrict__ projb,
    float* __restrict__ inv_out, unsigned short* __restrict__ h1b, int Nn)
{
    __shared__ uint2 sh[4][64];
    const int wid = threadIdx.x >> 6;
    const int d = blockIdx.x * 4 + wid;
    const int lane = threadIdx.x & 63;
    if (d >= Nn) return;
    const int beg = offs[d], end = offs[d + 1];
    const float2 qv = *(const float2*)&qd[2 * d];
    const char* pb = (const char*)projb;
    const int quarter = lane >> 4, l15 = lane & 15;
    const unsigned lb = (unsigned)(l15 << 4);            // 16B per lane
    uint2* shl = sh[wid];

    float exsum = 0.f;
    float2v a[4];
#pragma unroll
    for (int q = 0; q < 4; ++q) a[q] = (float2v){0.f, 0.f};

    for (int b = beg; b < end; b += 64) {
        const int i = b + lane;
        float ex = 0.f; unsigned off = 0;
        if (i < end) {
            const unsigned rx = recs[i];
            const int s = (int)(rx & 0xFFFFu), t = (int)(rx >> 16);
            float av = (t ? qv.y : qv.x) + kd[t * Nn + s];
            av = av > 0.f ? av : 0.2f * av;
            ex = __expf(av);
            off = ((unsigned)s << 9) | ((unsigned)t << 8);  // s*512 + t*256 bytes
        }
        shl[lane] = make_uint2(f2u(ex), off);
        exsum += ex;                                     // reduced once at end

        const int cnt = min(64, end - b);
        for (int j = 0; j < cnt; j += 16) {
            const uint2 p0 = shl[j + quarter];
            const uint2 p1 = shl[j + 4 + quarter];
            const uint2 p2 = shl[j + 8 + quarter];
            const uint2 p3 = shl[j + 12 + quarter];
            const uint4 v0 = *(const uint4*)(pb + (p0.y + lb));
            const uint4 v1 = *(const uint4*)(pb + (p1.y + lb));
            const uint4 v2 = *(const uint4*)(pb + (p2.y + lb));
            const uint4 v3 = *(const uint4*)(pb + (p3.y + lb));
            acc8p(u2f(p0.x), v0, a);
            acc8p(u2f(p1.x), v1, a);
            acc8p(u2f(p2.x), v2, a);
            acc8p(u2f(p3.x), v3, a);
        }
    }
#pragma unroll
    for (int o = 32; o; o >>= 1) exsum += __shfl_xor(exsum, o);
    const float inv = 1.f / (exsum + 1e-16f);
    if (lane == 0) inv_out[d] = inv;
#pragma unroll
    for (int q = 0; q < 4; ++q) {
        a[q][0] += __shfl_xor(a[q][0], 32);
        a[q][1] += __shfl_xor(a[q][1], 32);
        a[q][0] += __shfl_xor(a[q][0], 16);
        a[q][1] += __shfl_xor(a[q][1], 16);
    }
    if (quarter == 0) {
        ushort8 st;
#pragma unroll
        for (int q = 0; q < 8; ++q) {
            const float e = a[q >> 1][q & 1] * inv;
            st[q] = f2bf(e > 0.f ? e : expm1f(e));
        }
        *(ushort8*)&h1b[(long)d * 128 + (l15 << 3)] = st;   // dims l15*8..+7
    }
}

// -------- layer-2 fused, eighth-wave uint4 gather ------------------------------
// Row = 64 bf16 = 128B = 8 lanes x uint4; 8 edges per load, 4 loads in flight
// covering 32 edges per burst (avg degree 20 -> usually one burst per node).
__global__ __launch_bounds__(256) void aggr2_k(
    const int* __restrict__ offs, const unsigned* __restrict__ recs,
    const float* __restrict__ qd, const float* __restrict__ kd,
    const unsigned short* __restrict__ projb,
    float* __restrict__ inv_out, float* __restrict__ out,
    unsigned short* __restrict__ h2h, unsigned short* __restrict__ h2l, int Nn)
{
    __shared__ uint2 sh[4][64];
    const int wid = threadIdx.x >> 6;
    const int d = blockIdx.x * 4 + wid;
    const int lane = threadIdx.x & 63;
    if (d >= Nn) return;
    const int beg = offs[d], end = offs[d + 1];
    const float2 qv = *(const float2*)&qd[2 * d];
    const char* pb = (const char*)projb;
    const int eighth = lane >> 3, l7 = lane & 7;
    const unsigned lb = (unsigned)(l7 << 4);             // 16B per lane
    uint2* shl = sh[wid];

    float exsum = 0.f;
    float2v a[4];
#pragma unroll
    for (int q = 0; q < 4; ++q) a[q] = (float2v){0.f, 0.f};

    for (int b = beg; b < end; b += 64) {
        const int i = b + lane;
        float ex = 0.f; unsigned off = 0;
        if (i < end) {
            const unsigned rx = recs[i];
            const int s = (int)(rx & 0xFFFFu), t = (int)(rx >> 16);
            float av = (t ? qv.y : qv.x) + kd[t * Nn + s];
            av = av > 0.f ? av : 0.2f * av;
            ex = __expf(av);
            off = ((unsigned)s << 8) | ((unsigned)t << 7);  // s*256 + t*128 bytes
        }
        shl[lane] = make_uint2(f2u(ex), off);
        exsum += ex;

        const int cnt = min(64, end - b);
        for (int j = 0; j < cnt; j += 32) {
            const uint2 p0 = shl[j + eighth];
            const uint2 p1 = shl[j + 8 + eighth];
            const uint2 p2 = shl[j + 16 + eighth];
            const uint2 p3 = shl[j + 24 + eighth];
            const uint4 v0 = *(const uint4*)(pb + (p0.y + lb));
            const uint4 v1 = *(const uint4*)(pb + (p1.y + lb));
            const uint4 v2 = *(const uint4*)(pb + (p2.y + lb));
            const uint4 v3 = *(const uint4*)(pb + (p3.y + lb));
            acc8p(u2f(p0.x), v0, a);
            acc8p(u2f(p1.x), v1, a);
            acc8p(u2f(p2.x), v2, a);
            acc8p(u2f(p3.x), v3, a);
        }
    }
#pragma unroll
    for (int o = 32; o; o >>= 1) exsum += __shfl_xor(exsum, o);
    const float inv = 1.f / (exsum + 1e-16f);
    if (lane == 0) inv_out[d] = inv;
#pragma unroll
    for (int q = 0; q < 4; ++q) {
        a[q][0] += __shfl_xor(a[q][0], 32);
        a[q][1] += __shfl_xor(a[q][1], 32);
        a[q][0] += __shfl_xor(a[q][0], 16);
        a[q][1] += __shfl_xor(a[q][1], 16);
        a[q][0] += __shfl_xor(a[q][0], 8);
        a[q][1] += __shfl_xor(a[q][1], 8);
    }
    if (eighth == 0) {
        float vv[8];
#pragma unroll
        for (int q = 0; q < 8; ++q) {
            const float e = a[q >> 1][q & 1] * inv;
            vv[q] = e > 0.f ? e : expm1f(e);
        }
        float4 f0; f0.x = vv[0]; f0.y = vv[1]; f0.z = vv[2]; f0.w = vv[3];
        float4 f1; f1.x = vv[4]; f1.y = vv[5]; f1.z = vv[6]; f1.w = vv[7];
        *(float4*)&out[(long)d * 64 + (l7 << 3)] = f0;
        *(float4*)&out[(long)d * 64 + (l7 << 3) + 4] = f1;
        ushort8 hh, hl;
#pragma unroll
        for (int q = 0; q < 8; ++q) {
            const unsigned short hi = f2bf(vv[q]);
            hh[q] = hi; hl[q] = f2bf(vv[q] - bf2f(hi));
        }
        *(ushort8*)&h2h[(long)d * 64 + (l7 << 3)] = hh;
        *(ushort8*)&h2l[(long)d * 64 + (l7 << 3)] = hl;
    }
}

// -------- attention outputs: recompute alpha for both layers, one edge pass ----
// Identical FP expressions/inputs as the aggr kernels -> consistent softmax.
__global__ __launch_bounds__(256) void att_k(
    const int* __restrict__ srcv, const int* __restrict__ dstv,
    const int* __restrict__ et,
    const float* __restrict__ qd1, const float* __restrict__ kd1,
    const float* __restrict__ inv1,
    const float* __restrict__ qd2, const float* __restrict__ kd2,
    const float* __restrict__ inv2,
    float* __restrict__ att1, float* __restrict__ att2, int E, int Nn)
{
    const int e = blockIdx.x * 256 + threadIdx.x;
    if (e >= E) return;
    const int s = srcv[e], d = dstv[e], t = et[e];
    float x1 = qd1[2 * d + t] + kd1[t * Nn + s];
    x1 = x1 > 0.f ? x1 : 0.2f * x1;
    att1[e] = __expf(x1) * inv1[d];
    float x2 = qd2[2 * d + t] + kd2[t * Nn + s];
    x2 = x2 > 0.f ? x2 : 0.2f * x2;
    att2[e] = __expf(x2) * inv2[d];
}

extern "C" void kernel_launch(void* const* d_in, const int* in_sizes, int n_in,
                              void* d_out, int out_size, void* d_ws, size_t ws_size,
                              hipStream_t stream)
{
    const float* features = (const float*)d_in[0];
    const int*   eidx     = (const int*)d_in[1];
    const int*   etype    = (const int*)d_in[2];
    const float* W1       = (const float*)d_in[3];
    const float* q1       = (const float*)d_in[4];
    const float* k1       = (const float*)d_in[5];
    const float* W2       = (const float*)d_in[6];
    const float* q2       = (const float*)d_in[7];
    const float* k2       = (const float*)d_in[8];
    const float* dw1      = (const float*)d_in[9];
    const float* db1      = (const float*)d_in[10];
    const float* dw2      = (const float*)d_in[11];
    const float* db2      = (const float*)d_in[12];

    const int* srcv = eidx;
    const int* dstv = eidx + N_EDGE;

    float* out_h2 = (float*)d_out;                  // N x 64
    float* out_h3 = out_h2 + (long)N_NODES * OUT_D; // N x 256
    float* att1   = out_h3 + (long)N_NODES * IN_D;  // E
    float* att2   = att1 + N_EDGE;                  // E

    // ---- workspace carve-up ----
    // Liveness: rank aliases projb1's first 4 MB — rank dies at place_k, and
    // projb1 is first written by gemm_bf16_k which launches AFTER place_k.
    // cntp (line-padded counters, 3.2MB at [53.9M, 57.1M)) dies at scan1;
    // inv1/inv2 live at [53.5M, 53.9M), no overlap. recs starts at 57.3M.
    char* W = (char*)d_ws;
    int* rank = (int*)W;                                       // [0, 4M)  (aliases projb1)
    unsigned short* projb1 = (unsigned short*)(W);             // [0, 25.6M)
    unsigned short* projb2 = (unsigned short*)(W);             // alias
    unsigned short* hidh   = (unsigned short*)(W);             // [0, 12.8M) after aggr2
    unsigned short* hidl   = (unsigned short*)(W + 12800000);
    unsigned short* h1b    = (unsigned short*)(W + 25600000);  // [25.6M, 38.4M)
    unsigned short* h2h    = (unsigned short*)(W + 25600000 + 12800000);
    unsigned short* h2l    = (unsigned short*)(W + 25600000 + 19200000);
    float* qd1 = (float*)(W + 51200000);            // interleaved [node][2]
    float* kd1 = qd1 + 2 * N_NODES;
    float* qd2 = kd1 + 2 * N_NODES;
    float* kd2 = qd2 + 2 * N_NODES;
    int* offs   = (int*)(kd2 + 2 * N_NODES);        // [52.8M, 53.0M)
    int* bsum   = offs + N_NODES + 1;
    int* bpre   = bsum + 256;
    int* excl   = bpre + 256;                       // ends ~53.2M
    float* inv1 = (float*)(W + 53500000);           // [53.5M, 53.7M)
    float* inv2 = inv1 + N_NODES;                   // [53.7M, 53.9M)
    int* cntp   = (int*)(W + 53900000);             // [53.9M, 57.1M) padded counters
    unsigned* recs = (unsigned*)(W + 57300000);     // [57.3M, 61.3M)
    unsigned short* Wc1t = (unsigned short*)(W + 65300000);    // 65536 us
    unsigned short* Wc2t = Wc1t + 65536;                       // 16384 us
    unsigned short* dw1h = Wc2t + 16384;                       // 8192
    unsigned short* dw1l = dw1h + 8192;
    unsigned short* dw2h = dw1l + 8192;                        // 32768
    unsigned short* dw2l = dw2h + 32768;

    const int NB = (N_NODES + 255) / 256;
    const int MB128 = (N_NODES + 127) / 128;        // 391 row-tiles at BM=128

    // ---- prep: weight conversions (one kernel) + CSR build ----
    prep_k<<<480, 256, 0, stream>>>(W1, W2, dw1, dw2,
                                    Wc1t, Wc2t, dw1h, dw1l, dw2h, dw2l);

    hipMemsetAsync(cntp, 0, sizeof(int) * N_NODES * CPAD, stream);
    rank_k<<<(N_EDGE + 255) / 256, 256, 0, stream>>>(dstv, cntp, rank, N_EDGE);
    scan1_k<<<NB, 256, 0, stream>>>(cntp, excl, bsum, N_NODES);
    scan2_k<<<1, 256, 0, stream>>>(bsum, bpre, NB);
    scan3_k<<<NB, 256, 0, stream>>>(excl, bpre, offs, N_NODES, N_EDGE);
    place_k<<<(N_EDGE + 255) / 256, 256, 0, stream>>>(
        srcv, dstv, etype, rank, offs, recs, N_EDGE);

    // ---- layer 1 (features converted fp32->bf16 inside gemm staging) ----
    gemm_bf16_k<true><<<dim3(2, MB128), 256, 0, stream>>>(
        nullptr, features, Wc1t, projb1, N_NODES, IN_D, 2 * HID_D);
    dotsB_k<128><<<(int)(((long)N_NODES * 64 + 255) / 256), 256, 0, stream>>>(
        projb1, q1, k1, qd1, kd1, N_NODES);
    aggr1_k<<<(N_NODES + 3) / 4, 256, 0, stream>>>(
        offs, recs, qd1, kd1, projb1, inv1, h1b, N_NODES);

    // ---- layer 2 ----
    gemm_bf16_k<false><<<dim3(1, MB128), 256, 0, stream>>>(
        h1b, nullptr, Wc2t, projb2, N_NODES, HID_D, 2 * OUT_D);
    dotsB_k<64><<<(int)(((long)N_NODES * 64 + 255) / 256), 256, 0, stream>>>(
        projb2, q2, k2, qd2, kd2, N_NODES);
    aggr2_k<<<(N_NODES + 3) / 4, 256, 0, stream>>>(
        offs, recs, qd2, kd2, projb2, inv2, out_h2, h2h, h2l, N_NODES);

    // ---- attention outputs (both layers, one pass over E) ----
    att_k<<<(N_EDGE + 255) / 256, 256, 0, stream>>>(
        srcv, dstv, etype, qd1, kd1, inv1, qd2, kd2, inv2, att1, att2,
        N_EDGE, N_NODES);

    // ---- decoder (split-bf16 MFMA, fp32-accurate) ----
    dec_gemm_k<true><<<dim3(1, MB128), 256, 0, stream>>>(
        h2h, h2l, dw1h, dw1l, db1, nullptr, hidh, hidl, N_NODES, OUT_D, HID_D);
    dec_gemm_k<false><<<dim3(2, MB128), 256, 0, stream>>>(
        hidh, hidl, dw2h, dw2l, db2, out_h3, nullptr, nullptr, N_NODES, HID_D, IN_D);
}

// Round 9
// 385.143 us; speedup vs baseline: 1.0409x; 1.0409x over previous
//
#include <hip/hip_runtime.h>
#include <hip/hip_bf16.h>

static constexpr int N_NODES = 50000;
static constexpr int N_EDGE  = 1000000;
static constexpr int IN_D    = 256;
static constexpr int HID_D   = 128;
static constexpr int OUT_D   = 64;
static constexpr int R_REL   = 2;

typedef __attribute__((ext_vector_type(8))) short short8;            // 8 bf16 = 4 VGPRs
typedef __attribute__((ext_vector_type(8))) unsigned short ushort8;  // store type
typedef __attribute__((ext_vector_type(4))) float float4v;

static __device__ __forceinline__ unsigned short f2bf(float v) {
    __hip_bfloat16 h = __float2bfloat16(v);
    return *(unsigned short*)&h;
}
static __device__ __forceinline__ float bf2f(unsigned short u) {
    union { unsigned int i; float f; } c; c.i = ((unsigned int)u) << 16; return c.f;
}
// low/high bf16 of a packed u32 -> f32 (1 VALU each: lshl / and)
static __device__ __forceinline__ float bflo(unsigned u) {
    union { unsigned i; float f; } c; c.i = u << 16; return c.f;
}
static __device__ __forceinline__ float bfhi(unsigned u) {
    union { unsigned i; float f; } c; c.i = u & 0xFFFF0000u; return c.f;
}
static __device__ __forceinline__ float u2f(unsigned u) {
    union { unsigned i; float f; } c; c.i = u; return c.f;
}
static __device__ __forceinline__ unsigned f2u(float f) {
    union { unsigned i; float f; } c; c.f = f; return c.i;
}
// accumulate 8 bf16 (one uint4) scaled by w into a[0..7]  (round-7 verified;
// round-8's pk_fma variant was neutral-to-negative -> reverted)
static __device__ __forceinline__ void acc8(float w, uint4 v, float (&a)[8]) {
    a[0] = fmaf(w, bflo(v.x), a[0]); a[1] = fmaf(w, bfhi(v.x), a[1]);
    a[2] = fmaf(w, bflo(v.y), a[2]); a[3] = fmaf(w, bfhi(v.y), a[3]);
    a[4] = fmaf(w, bflo(v.z), a[4]); a[5] = fmaf(w, bfhi(v.z), a[5]);
    a[6] = fmaf(w, bflo(v.w), a[6]); a[7] = fmaf(w, bfhi(v.w), a[7]);
}

// ---- merged prep: weight convert/split + zero-init of qd/kd and cntp --------
// (folds the old hipMemsetAsync + gives atomic-dot targets a zeroed base)
__global__ __launch_bounds__(256) void prep_k(
    const float* __restrict__ W1, const float* __restrict__ W2,
    const float* __restrict__ dw1, const float* __restrict__ dw2,
    unsigned short* __restrict__ Wc1t, unsigned short* __restrict__ Wc2t,
    unsigned short* __restrict__ dw1h, unsigned short* __restrict__ dw1l,
    unsigned short* __restrict__ dw2h, unsigned short* __restrict__ dw2l,
    uint4* __restrict__ zeroA, uint4* __restrict__ zeroB)
{
    int idx = blockIdx.x * 256 + threadIdx.x;
    if (idx < R_REL * HID_D * IN_D) {                       // 65536
        const int n = idx / IN_D, kk = idx % IN_D;
        const int r = n / HID_D, o = n % HID_D;
        Wc1t[(long)n * IN_D + kk] = f2bf(W1[((long)r * IN_D + kk) * HID_D + o]);
        return;
    }
    idx -= R_REL * HID_D * IN_D;
    if (idx < R_REL * OUT_D * HID_D) {                      // 16384
        const int n = idx / HID_D, kk = idx % HID_D;
        const int r = n / OUT_D, o = n % OUT_D;
        Wc2t[(long)n * HID_D + kk] = f2bf(W2[((long)r * HID_D + kk) * OUT_D + o]);
        return;
    }
    idx -= R_REL * OUT_D * HID_D;
    if (idx < HID_D * OUT_D) {                              // 8192
        const float v = dw1[idx];
        const unsigned short hi = f2bf(v);
        dw1h[idx] = hi; dw1l[idx] = f2bf(v - bf2f(hi));
        return;
    }
    idx -= HID_D * OUT_D;
    if (idx < IN_D * HID_D) {                               // 32768
        const float v = dw2[idx];
        const unsigned short hi = f2bf(v);
        dw2h[idx] = hi; dw2l[idx] = f2bf(v - bf2f(hi));
        return;
    }
    idx -= IN_D * HID_D;
    if (idx < 100000) {                                     // qd1/kd1/qd2/kd2: 400000 ints
        zeroA[idx] = make_uint4(0, 0, 0, 0);
        return;
    }
    idx -= 100000;
    if (idx < 200000) {                                     // cntp: 800000 ints
        zeroB[idx] = make_uint4(0, 0, 0, 0);
    }
}

// ---------------- bf16 MFMA GEMM: Cb[M,N] (bf16) = A[M,K] @ Bt[N,K]^T ----------
// BM=128 + spill-free register prefetch in NAMED registers (macro-assigned).
// CVT=true: A is fp32, converted to bf16 in registers during LDS commit.
// Fused q/k dot epilogue: relation r = (bn+wn)/Dq is wave-uniform; partial dot
// over this wave's 64 cols reduced via shfl over l15, atomicAdd into qdo/kdo
// (zeroed by prep_k). Removes the dotsB kernels + their projb re-read, and
// computes dots from fp32 acc (closer to the fp32 reference than bf16 projb).
template<bool CVT>
__global__ __launch_bounds__(256) void gemm_bf16_k(
    const unsigned short* __restrict__ A, const float* __restrict__ Af,
    const unsigned short* __restrict__ Bt,
    unsigned short* __restrict__ Cb,
    const float* __restrict__ qvec, const float* __restrict__ kvec,
    float* __restrict__ qdo, float* __restrict__ kdo, int Dq,
    int M, int K, int Nn)
{
    constexpr int BM = 128;
    constexpr int LDK = 40;   // 80 B rows: 16B-aligned, 2-way-only bank conflicts
    __shared__ __align__(16) unsigned short As[BM * LDK];
    __shared__ __align__(16) unsigned short Bs[128 * LDK];

    const int tid = threadIdx.x;
    const int wave = tid >> 6, lane = tid & 63;
    const int wm = (wave >> 1) * 64;
    const int wn = (wave & 1) * 64;
    const int bm = blockIdx.y * BM;
    const int bn = blockIdx.x * 128;
    const int l15 = lane & 15, quad = lane >> 4;

    const int ar0 = tid >> 2,          ach0 = (tid & 3) * 8;
    const int ar1 = (tid + 256) >> 2,  ach1 = (tid & 3) * 8;   // (tid+256)&3 == tid&3
    const long ga0 = (long)min(bm + ar0, M - 1) * K + ach0;
    const long ga1 = (long)min(bm + ar1, M - 1) * K + ach1;
    const long gb0 = (long)(bn + ar0) * K + ach0;
    const long gb1 = (long)(bn + ar1) * K + ach1;

    float4 fa0, fa1, fa2, fa3;   // CVT prefetch (fp32, 2 chunks x 2 float4)
    uint4  qa0, qa1;             // bf16 prefetch
    uint4  qb0, qb1;             // B prefetch

#define GEMM_PREF(k0) do {                                                  \
    if constexpr (CVT) {                                                    \
        fa0 = *(const float4*)&Af[ga0 + (k0)];                              \
        fa1 = *(const float4*)&Af[ga0 + (k0) + 4];                          \
        fa2 = *(const float4*)&Af[ga1 + (k0)];                              \
        fa3 = *(const float4*)&Af[ga1 + (k0) + 4];                          \
    } else {                                                                \
        qa0 = *(const uint4*)&A[ga0 + (k0)];                                \
        qa1 = *(const uint4*)&A[ga1 + (k0)];                                \
    }                                                                       \
    qb0 = *(const uint4*)&Bt[gb0 + (k0)];                                   \
    qb1 = *(const uint4*)&Bt[gb1 + (k0)];                                   \
} while (0)

#define GEMM_COMMIT() do {                                                  \
    if constexpr (CVT) {                                                    \
        uint4 o0, o1;                                                       \
        o0.x = (unsigned)f2bf(fa0.x) | ((unsigned)f2bf(fa0.y) << 16);       \
        o0.y = (unsigned)f2bf(fa0.z) | ((unsigned)f2bf(fa0.w) << 16);       \
        o0.z = (unsigned)f2bf(fa1.x) | ((unsigned)f2bf(fa1.y) << 16);       \
        o0.w = (unsigned)f2bf(fa1.z) | ((unsigned)f2bf(fa1.w) << 16);       \
        o1.x = (unsigned)f2bf(fa2.x) | ((unsigned)f2bf(fa2.y) << 16);       \
        o1.y = (unsigned)f2bf(fa2.z) | ((unsigned)f2bf(fa2.w) << 16);       \
        o1.z = (unsigned)f2bf(fa3.x) | ((unsigned)f2bf(fa3.y) << 16);       \
        o1.w = (unsigned)f2bf(fa3.z) | ((unsigned)f2bf(fa3.w) << 16);       \
        *(uint4*)&As[ar0 * LDK + ach0] = o0;                                \
        *(uint4*)&As[ar1 * LDK + ach1] = o1;                                \
    } else {                                                                \
        *(uint4*)&As[ar0 * LDK + ach0] = qa0;                               \
        *(uint4*)&As[ar1 * LDK + ach1] = qa1;                               \
    }                                                                       \
    *(uint4*)&Bs[ar0 * LDK + ach0] = qb0;                                   \
    *(uint4*)&Bs[ar1 * LDK + ach1] = qb1;                                   \
} while (0)

    float4v acc[4][4];
#pragma unroll
    for (int i = 0; i < 4; ++i)
#pragma unroll
        for (int j = 0; j < 4; ++j) acc[i][j] = (float4v){0.f, 0.f, 0.f, 0.f};

    GEMM_PREF(0);
    for (int k0 = 0; k0 < K; k0 += 32) {
        GEMM_COMMIT();
        __syncthreads();
        if (k0 + 32 < K) GEMM_PREF(k0 + 32);   // in flight across MFMA phase

        short8 bfrag[4];
#pragma unroll
        for (int nt = 0; nt < 4; ++nt)
            bfrag[nt] = *(const short8*)&Bs[(wn + nt * 16 + l15) * LDK + quad * 8];
#pragma unroll
        for (int mt = 0; mt < 4; ++mt) {
            const short8 afrag = *(const short8*)&As[(wm + mt * 16 + l15) * LDK + quad * 8];
#pragma unroll
            for (int nt = 0; nt < 4; ++nt)
                acc[mt][nt] = __builtin_amdgcn_mfma_f32_16x16x32_bf16(
                    afrag, bfrag[nt], acc[mt][nt], 0, 0, 0);
        }
        __syncthreads();
    }
#undef GEMM_PREF
#undef GEMM_COMMIT

    // C/D layout: col = lane&15, row = quad*4 + reg (m89-verified)
#pragma unroll
    for (int mt = 0; mt < 4; ++mt)
#pragma unroll
        for (int nt = 0; nt < 4; ++nt) {
            const int n = bn + wn + nt * 16 + l15;
#pragma unroll
            for (int rg = 0; rg < 4; ++rg) {
                const int m = bm + wm + mt * 16 + quad * 4 + rg;
                if (m < M) Cb[(long)m * Nn + n] = f2bf(acc[mt][nt][rg]);
            }
        }

    // ---- fused q/k dot epilogue ----
    {
        const int r = (bn + wn) / Dq;               // wave-uniform relation
        const int obase = bn + wn - r * Dq + l15;   // o index for nt=0
#pragma unroll
        for (int mt = 0; mt < 4; ++mt)
#pragma unroll
            for (int rg = 0; rg < 4; ++rg) {
                float qp = 0.f, kp = 0.f;
#pragma unroll
                for (int nt = 0; nt < 4; ++nt) {
                    const float cv = acc[mt][nt][rg];
                    qp = fmaf(cv, qvec[obase + nt * 16], qp);
                    kp = fmaf(cv, kvec[obase + nt * 16], kp);
                }
                qp += __shfl_xor(qp, 1); kp += __shfl_xor(kp, 1);
                qp += __shfl_xor(qp, 2); kp += __shfl_xor(kp, 2);
                qp += __shfl_xor(qp, 4); kp += __shfl_xor(kp, 4);
                qp += __shfl_xor(qp, 8); kp += __shfl_xor(kp, 8);
                if (l15 == 0) {
                    const int m = bm + wm + mt * 16 + quad * 4 + rg;
                    if (m < M) {
                        atomicAdd(&qdo[2 * m + r], qp);
                        atomicAdd(&kdo[(long)r * M + m], kp);
                    }
                }
            }
    }
}

// -------- decoder split-bf16 MFMA GEMM: C = (Ah+Al)(Bh+Bl)^T + bias ------------
// Same spill-free named-register prefetch, 4 input streams.
template<bool SPLITOUT>
__global__ __launch_bounds__(256) void dec_gemm_k(
    const unsigned short* __restrict__ Ah, const unsigned short* __restrict__ Al,
    const unsigned short* __restrict__ Bh, const unsigned short* __restrict__ Bl,
    const float* __restrict__ bias, float* __restrict__ Cf,
    unsigned short* __restrict__ Ch, unsigned short* __restrict__ Cl,
    int M, int K, int Nn)
{
    constexpr int BM = 128;
    constexpr int LDK = 40;
    __shared__ __align__(16) unsigned short Ash[BM * LDK];
    __shared__ __align__(16) unsigned short Asl[BM * LDK];
    __shared__ __align__(16) unsigned short Bsh[128 * LDK];
    __shared__ __align__(16) unsigned short Bsl[128 * LDK];

    const int tid = threadIdx.x;
    const int wave = tid >> 6, lane = tid & 63;
    const int wm = (wave >> 1) * 64;
    const int wn = (wave & 1) * 64;
    const int bm = blockIdx.y * BM;
    const int bn = blockIdx.x * 128;
    const int l15 = lane & 15, quad = lane >> 4;

    const int ar0 = tid >> 2,          ach0 = (tid & 3) * 8;
    const int ar1 = (tid + 256) >> 2,  ach1 = (tid & 3) * 8;
    const long ga0 = (long)min(bm + ar0, M - 1) * K + ach0;
    const long ga1 = (long)min(bm + ar1, M - 1) * K + ach1;
    const long gb0 = (long)(bn + ar0) * K + ach0;
    const long gb1 = (long)(bn + ar1) * K + ach1;

    uint4 ph0, ph1, pl0, pl1;     // A hi/lo prefetch
    uint4 rh0, rh1, rl0, rl1;     // B hi/lo prefetch

#define DEC_PREF(k0) do {                                   \
    ph0 = *(const uint4*)&Ah[ga0 + (k0)];                   \
    ph1 = *(const uint4*)&Ah[ga1 + (k0)];                   \
    pl0 = *(const uint4*)&Al[ga0 + (k0)];                   \
    pl1 = *(const uint4*)&Al[ga1 + (k0)];                   \
    rh0 = *(const uint4*)&Bh[gb0 + (k0)];                   \
    rh1 = *(const uint4*)&Bh[gb1 + (k0)];                   \
    rl0 = *(const uint4*)&Bl[gb0 + (k0)];                   \
    rl1 = *(const uint4*)&Bl[gb1 + (k0)];                   \
} while (0)

#define DEC_COMMIT() do {                                   \
    *(uint4*)&Ash[ar0 * LDK + ach0] = ph0;                  \
    *(uint4*)&Ash[ar1 * LDK + ach1] = ph1;                  \
    *(uint4*)&Asl[ar0 * LDK + ach0] = pl0;                  \
    *(uint4*)&Asl[ar1 * LDK + ach1] = pl1;                  \
    *(uint4*)&Bsh[ar0 * LDK + ach0] = rh0;                  \
    *(uint4*)&Bsh[ar1 * LDK + ach1] = rh1;                  \
    *(uint4*)&Bsl[ar0 * LDK + ach0] = rl0;                  \
    *(uint4*)&Bsl[ar1 * LDK + ach1] = rl1;                  \
} while (0)

    float4v acc[4][4];
#pragma unroll
    for (int i = 0; i < 4; ++i)
#pragma unroll
        for (int j = 0; j < 4; ++j) acc[i][j] = (float4v){0.f, 0.f, 0.f, 0.f};

    DEC_PREF(0);
    for (int k0 = 0; k0 < K; k0 += 32) {
        DEC_COMMIT();
        __syncthreads();
        if (k0 + 32 < K) DEC_PREF(k0 + 32);

        short8 bh[4], bl[4];
#pragma unroll
        for (int nt = 0; nt < 4; ++nt) {
            bh[nt] = *(const short8*)&Bsh[(wn + nt * 16 + l15) * LDK + quad * 8];
            bl[nt] = *(const short8*)&Bsl[(wn + nt * 16 + l15) * LDK + quad * 8];
        }
#pragma unroll
        for (int mt = 0; mt < 4; ++mt) {
            const short8 ah = *(const short8*)&Ash[(wm + mt * 16 + l15) * LDK + quad * 8];
            const short8 al = *(const short8*)&Asl[(wm + mt * 16 + l15) * LDK + quad * 8];
#pragma unroll
            for (int nt = 0; nt < 4; ++nt) {
                acc[mt][nt] = __builtin_amdgcn_mfma_f32_16x16x32_bf16(ah, bh[nt], acc[mt][nt], 0, 0, 0);
                acc[mt][nt] = __builtin_amdgcn_mfma_f32_16x16x32_bf16(al, bh[nt], acc[mt][nt], 0, 0, 0);
                acc[mt][nt] = __builtin_amdgcn_mfma_f32_16x16x32_bf16(ah, bl[nt], acc[mt][nt], 0, 0, 0);
            }
        }
        __syncthreads();
    }
#undef DEC_PREF
#undef DEC_COMMIT

#pragma unroll
    for (int mt = 0; mt < 4; ++mt)
#pragma unroll
        for (int nt = 0; nt < 4; ++nt) {
            const int n = bn + wn + nt * 16 + l15;
            const float bv = bias[n];
#pragma unroll
            for (int rg = 0; rg < 4; ++rg) {
                const int m = bm + wm + mt * 16 + quad * 4 + rg;
                if (m >= M) continue;
                const float v = acc[mt][nt][rg] + bv;
                if (SPLITOUT) {
                    const unsigned short hi = f2bf(v);
                    Ch[(long)m * Nn + n] = hi;
                    Cl[(long)m * Nn + n] = f2bf(v - bf2f(hi));
                } else {
                    Cf[(long)m * Nn + n] = v;
                }
            }
        }
}

// ---------------- CSR build (rank/scan/place — no atomic->scatter chain) -------
// rank_k atomics go to a line-padded counter array (stride 16 ints = 64B/node).
static constexpr int CPAD = 16;   // ints per counter slot (64 B)

__global__ __launch_bounds__(256) void rank_k(
    const int* __restrict__ dstv, int* __restrict__ cntp,
    int* __restrict__ rank, int E)
{
    const int e = blockIdx.x * blockDim.x + threadIdx.x;
    if (e >= E) return;
    rank[e] = atomicAdd(&cntp[dstv[e] * CPAD], 1);
}

__global__ __launch_bounds__(256) void scan1_k(
    const int* __restrict__ cntp, int* __restrict__ excl_out,
    int* __restrict__ bsum, int n)
{
    __shared__ int s[256];
    const int t = threadIdx.x;
    const int i = blockIdx.x * 256 + t;
    const int v = (i < n) ? cntp[i * CPAD] : 0;
    s[t] = v;
    __syncthreads();
    for (int off = 1; off < 256; off <<= 1) {
        const int x = (t >= off) ? s[t - off] : 0;
        __syncthreads();
        s[t] += x;
        __syncthreads();
    }
    if (i < n) excl_out[i] = s[t] - v;
    if (t == 255) bsum[blockIdx.x] = s[255];
}

// scan2 merged into scan3: every block redundantly scans the <=256 block sums
// in LDS (cheap) and picks its own exclusive prefix — saves a kernel launch.
__global__ __launch_bounds__(256) void scan23_k(
    const int* __restrict__ excl, const int* __restrict__ bsum,
    int* __restrict__ offs, int n, int total, int nb)
{
    __shared__ int s[256];
    __shared__ int base;
    const int t = threadIdx.x;
    const int v = (t < nb) ? bsum[t] : 0;
    s[t] = v;
    __syncthreads();
    for (int off = 1; off < 256; off <<= 1) {
        const int x = (t >= off) ? s[t - off] : 0;
        __syncthreads();
        s[t] += x;
        __syncthreads();
    }
    if (t == (int)blockIdx.x) base = s[t] - v;   // exclusive prefix for this block
    __syncthreads();
    const int i = blockIdx.x * 256 + t;
    if (i < n) offs[i] = excl[i] + base;
    if (i == 0) offs[n] = total;
}

// place_k: deterministic position, single 4B record write, no atomics.
// record = (etype << 16) | src   (src < 65536 since N_NODES = 50000)
__global__ __launch_bounds__(256) void place_k(
    const int* __restrict__ srcv, const int* __restrict__ dstv,
    const int* __restrict__ et, const int* __restrict__ rank,
    const int* __restrict__ offs, unsigned* __restrict__ recs, int E)
{
    const int e = blockIdx.x * blockDim.x + threadIdx.x;
    if (e >= E) return;
    const int pos = offs[dstv[e]] + rank[e];
    recs[pos] = (unsigned)((et[e] << 16) | srcv[e]);
}

// -------- layer-1 fused softmax+aggr+ELU, quarter-wave uint4 gather ------------
// Row = 128 bf16 = 256B = 16 lanes x uint4; 4 edges per load, 4 loads in flight
// covering 16 edges per burst. No attention writes here (att_k recomputes).
__global__ __launch_bounds__(256) void aggr1_k(
    const int* __restrict__ offs, const unsigned* __restrict__ recs,
    const float* __restrict__ qd, const float* __restrict__ kd,
    const unsigned short* __restrict__ projb,
    float* __restrict__ inv_out, unsigned short* __restrict__ h1b, int Nn)
{
    __shared__ uint2 sh[4][64];
    const int wid = threadIdx.x >> 6;
    const int d = blockIdx.x * 4 + wid;
    const int lane = threadIdx.x & 63;
    if (d >= Nn) return;
    const int beg = offs[d], end = offs[d + 1];
    const float2 qv = *(const float2*)&qd[2 * d];
    const char* pb = (const char*)projb;
    const int quarter = lane >> 4, l15 = lane & 15;
    const unsigned lb = (unsigned)(l15 << 4);            // 16B per lane
    uint2* shl = sh[wid];

    float exsum = 0.f;
    float a[8] = {0.f, 0.f, 0.f, 0.f, 0.f, 0.f, 0.f, 0.f};

    for (int b = beg; b < end; b += 64) {
        const int i = b + lane;
        float ex = 0.f; unsigned off = 0;
        if (i < end) {
            const unsigned rx = recs[i];
            const int s = (int)(rx & 0xFFFFu), t = (int)(rx >> 16);
            float av = (t ? qv.y : qv.x) + kd[t * Nn + s];
            av = av > 0.f ? av : 0.2f * av;
            ex = __expf(av);
            off = ((unsigned)s << 9) | ((unsigned)t << 8);  // s*512 + t*256 bytes
        }
        shl[lane] = make_uint2(f2u(ex), off);
        exsum += ex;                                     // reduced once at end

        const int cnt = min(64, end - b);
        for (int j = 0; j < cnt; j += 16) {
            const uint2 p0 = shl[j + quarter];
            const uint2 p1 = shl[j + 4 + quarter];
            const uint2 p2 = shl[j + 8 + quarter];
            const uint2 p3 = shl[j + 12 + quarter];
            const uint4 v0 = *(const uint4*)(pb + (p0.y + lb));
            const uint4 v1 = *(const uint4*)(pb + (p1.y + lb));
            const uint4 v2 = *(const uint4*)(pb + (p2.y + lb));
            const uint4 v3 = *(const uint4*)(pb + (p3.y + lb));
            acc8(u2f(p0.x), v0, a);
            acc8(u2f(p1.x), v1, a);
            acc8(u2f(p2.x), v2, a);
            acc8(u2f(p3.x), v3, a);
        }
    }
#pragma unroll
    for (int o = 32; o; o >>= 1) exsum += __shfl_xor(exsum, o);
    const float inv = 1.f / (exsum + 1e-16f);
    if (lane == 0) inv_out[d] = inv;
#pragma unroll
    for (int q = 0; q < 8; ++q) {
        a[q] += __shfl_xor(a[q], 32);
        a[q] += __shfl_xor(a[q], 16);
    }
    if (quarter == 0) {
        ushort8 st;
#pragma unroll
        for (int q = 0; q < 8; ++q) {
            const float e = a[q] * inv;
            st[q] = f2bf(e > 0.f ? e : expm1f(e));
        }
        *(ushort8*)&h1b[(long)d * 128 + (l15 << 3)] = st;   // dims l15*8..+7
    }
}

// -------- layer-2 fused, eighth-wave uint4 gather ------------------------------
// Row = 64 bf16 = 128B = 8 lanes x uint4; 8 edges per load, 4 loads in flight
// covering 32 edges per burst (avg degree 20 -> usually one burst per node).
__global__ __launch_bounds__(256) void aggr2_k(
    const int* __restrict__ offs, const unsigned* __restrict__ recs,
    const float* __restrict__ qd, const float* __restrict__ kd,
    const unsigned short* __restrict__ projb,
    float* __restrict__ inv_out, float* __restrict__ out,
    unsigned short* __restrict__ h2h, unsigned short* __restrict__ h2l, int Nn)
{
    __shared__ uint2 sh[4][64];
    const int wid = threadIdx.x >> 6;
    const int d = blockIdx.x * 4 + wid;
    const int lane = threadIdx.x & 63;
    if (d >= Nn) return;
    const int beg = offs[d], end = offs[d + 1];
    const float2 qv = *(const float2*)&qd[2 * d];
    const char* pb = (const char*)projb;
    const int eighth = lane >> 3, l7 = lane & 7;
    const unsigned lb = (unsigned)(l7 << 4);             // 16B per lane
    uint2* shl = sh[wid];

    float exsum = 0.f;
    float a[8] = {0.f, 0.f, 0.f, 0.f, 0.f, 0.f, 0.f, 0.f};

    for (int b = beg; b < end; b += 64) {
        const int i = b + lane;
        float ex = 0.f; unsigned off = 0;
        if (i < end) {
            const unsigned rx = recs[i];
            const int s = (int)(rx & 0xFFFFu), t = (int)(rx >> 16);
            float av = (t ? qv.y : qv.x) + kd[t * Nn + s];
            av = av > 0.f ? av : 0.2f * av;
            ex = __expf(av);
            off = ((unsigned)s << 8) | ((unsigned)t << 7);  // s*256 + t*128 bytes
        }
        shl[lane] = make_uint2(f2u(ex), off);
        exsum += ex;

        const int cnt = min(64, end - b);
        for (int j = 0; j < cnt; j += 32) {
            const uint2 p0 = shl[j + eighth];
            const uint2 p1 = shl[j + 8 + eighth];
            const uint2 p2 = shl[j + 16 + eighth];
            const uint2 p3 = shl[j + 24 + eighth];
            const uint4 v0 = *(const uint4*)(pb + (p0.y + lb));
            const uint4 v1 = *(const uint4*)(pb + (p1.y + lb));
            const uint4 v2 = *(const uint4*)(pb + (p2.y + lb));
            const uint4 v3 = *(const uint4*)(pb + (p3.y + lb));
            acc8(u2f(p0.x), v0, a);
            acc8(u2f(p1.x), v1, a);
            acc8(u2f(p2.x), v2, a);
            acc8(u2f(p3.x), v3, a);
        }
    }
#pragma unroll
    for (int o = 32; o; o >>= 1) exsum += __shfl_xor(exsum, o);
    const float inv = 1.f / (exsum + 1e-16f);
    if (lane == 0) inv_out[d] = inv;
#pragma unroll
    for (int q = 0; q < 8; ++q) {
        a[q] += __shfl_xor(a[q], 32);
        a[q] += __shfl_xor(a[q], 16);
        a[q] += __shfl_xor(a[q], 8);
    }
    if (eighth == 0) {
        float vv[8];
#pragma unroll
        for (int q = 0; q < 8; ++q) {
            const float e = a[q] * inv;
            vv[q] = e > 0.f ? e : expm1f(e);
        }
        float4 f0; f0.x = vv[0]; f0.y = vv[1]; f0.z = vv[2]; f0.w = vv[3];
        float4 f1; f1.x = vv[4]; f1.y = vv[5]; f1.z = vv[6]; f1.w = vv[7];
        *(float4*)&out[(long)d * 64 + (l7 << 3)] = f0;
        *(float4*)&out[(long)d * 64 + (l7 << 3) + 4] = f1;
        ushort8 hh, hl;
#pragma unroll
        for (int q = 0; q < 8; ++q) {
            const unsigned short hi = f2bf(vv[q]);
            hh[q] = hi; hl[q] = f2bf(vv[q] - bf2f(hi));
        }
        *(ushort8*)&h2h[(long)d * 64 + (l7 << 3)] = hh;
        *(ushort8*)&h2l[(long)d * 64 + (l7 << 3)] = hl;
    }
}

// -------- attention outputs: recompute alpha for both layers, one edge pass ----
// Identical FP expressions/inputs as the aggr kernels -> consistent softmax.
__global__ __launch_bounds__(256) void att_k(
    const int* __restrict__ srcv, const int* __restrict__ dstv,
    const int* __restrict__ et,
    const float* __restrict__ qd1, const float* __restrict__ kd1,
    const float* __restrict__ inv1,
    const float* __restrict__ qd2, const float* __restrict__ kd2,
    const float* __restrict__ inv2,
    float* __restrict__ att1, float* __restrict__ att2, int E, int Nn)
{
    const int e = blockIdx.x * 256 + threadIdx.x;
    if (e >= E) return;
    const int s = srcv[e], d = dstv[e], t = et[e];
    float x1 = qd1[2 * d + t] + kd1[t * Nn + s];
    x1 = x1 > 0.f ? x1 : 0.2f * x1;
    att1[e] = __expf(x1) * inv1[d];
    float x2 = qd2[2 * d + t] + kd2[t * Nn + s];
    x2 = x2 > 0.f ? x2 : 0.2f * x2;
    att2[e] = __expf(x2) * inv2[d];
}

extern "C" void kernel_launch(void* const* d_in, const int* in_sizes, int n_in,
                              void* d_out, int out_size, void* d_ws, size_t ws_size,
                              hipStream_t stream)
{
    const float* features = (const float*)d_in[0];
    const int*   eidx     = (const int*)d_in[1];
    const int*   etype    = (const int*)d_in[2];
    const float* W1       = (const float*)d_in[3];
    const float* q1       = (const float*)d_in[4];
    const float* k1       = (const float*)d_in[5];
    const float* W2       = (const float*)d_in[6];
    const float* q2       = (const float*)d_in[7];
    const float* k2       = (const float*)d_in[8];
    const float* dw1      = (const float*)d_in[9];
    const float* db1      = (const float*)d_in[10];
    const float* dw2      = (const float*)d_in[11];
    const float* db2      = (const float*)d_in[12];

    const int* srcv = eidx;
    const int* dstv = eidx + N_EDGE;

    float* out_h2 = (float*)d_out;                  // N x 64
    float* out_h3 = out_h2 + (long)N_NODES * OUT_D; // N x 256
    float* att1   = out_h3 + (long)N_NODES * IN_D;  // E
    float* att2   = att1 + N_EDGE;                  // E

    // ---- workspace carve-up ----
    // Liveness: rank aliases projb1's first 4 MB — rank dies at place_k, and
    // projb1 is first written by gemm_bf16_k which launches AFTER place_k.
    // cntp (line-padded counters, 3.2MB at [53.9M, 57.1M)) dies at scan1;
    // inv1/inv2 live at [53.5M, 53.9M), no overlap. recs starts at 57.3M.
    // qd/kd (contiguous [51.2M, 52.8M)) are zeroed by prep_k and filled by
    // the gemm dot-epilogue atomics.
    char* W = (char*)d_ws;
    int* rank = (int*)W;                                       // [0, 4M)  (aliases projb1)
    unsigned short* projb1 = (unsigned short*)(W);             // [0, 25.6M)
    unsigned short* projb2 = (unsigned short*)(W);             // alias
    unsigned short* hidh   = (unsigned short*)(W);             // [0, 12.8M) after aggr2
    unsigned short* hidl   = (unsigned short*)(W + 12800000);
    unsigned short* h1b    = (unsigned short*)(W + 25600000);  // [25.6M, 38.4M)
    unsigned short* h2h    = (unsigned short*)(W + 25600000 + 12800000);
    unsigned short* h2l    = (unsigned short*)(W + 25600000 + 19200000);
    float* qd1 = (float*)(W + 51200000);            // interleaved [node][2]
    float* kd1 = qd1 + 2 * N_NODES;
    float* qd2 = kd1 + 2 * N_NODES;
    float* kd2 = qd2 + 2 * N_NODES;
    int* offs   = (int*)(kd2 + 2 * N_NODES);        // [52.8M, 53.0M)
    int* bsum   = offs + N_NODES + 1;
    int* bpre   = bsum + 256;                       // (unused slot kept for layout)
    int* excl   = bpre + 256;                       // ends ~53.2M
    float* inv1 = (float*)(W + 53500000);           // [53.5M, 53.7M)
    float* inv2 = inv1 + N_NODES;                   // [53.7M, 53.9M)
    int* cntp   = (int*)(W + 53900000);             // [53.9M, 57.1M) padded counters
    unsigned* recs = (unsigned*)(W + 57300000);     // [57.3M, 61.3M)
    unsigned short* Wc1t = (unsigned short*)(W + 65300000);    // 65536 us
    unsigned short* Wc2t = Wc1t + 65536;                       // 16384 us
    unsigned short* dw1h = Wc2t + 16384;                       // 8192
    unsigned short* dw1l = dw1h + 8192;
    unsigned short* dw2h = dw1l + 8192;                        // 32768
    unsigned short* dw2l = dw2h + 32768;

    const int NB = (N_NODES + 255) / 256;
    const int MB128 = (N_NODES + 127) / 128;        // 391 row-tiles at BM=128

    // ---- prep: weight conversions + zero-init (qd/kd, cntp) in one kernel ----
    // tasks: 122880 weight elems + 100000 uint4 (qd/kd) + 200000 uint4 (cntp)
    prep_k<<<1652, 256, 0, stream>>>(W1, W2, dw1, dw2,
                                     Wc1t, Wc2t, dw1h, dw1l, dw2h, dw2l,
                                     (uint4*)qd1, (uint4*)cntp);

    rank_k<<<(N_EDGE + 255) / 256, 256, 0, stream>>>(dstv, cntp, rank, N_EDGE);
    scan1_k<<<NB, 256, 0, stream>>>(cntp, excl, bsum, N_NODES);
    scan23_k<<<NB, 256, 0, stream>>>(excl, bsum, offs, N_NODES, N_EDGE, NB);
    place_k<<<(N_EDGE + 255) / 256, 256, 0, stream>>>(
        srcv, dstv, etype, rank, offs, recs, N_EDGE);

    // ---- layer 1 (fp32->bf16 fused staging + fused q/k dot epilogue) ----
    gemm_bf16_k<true><<<dim3(2, MB128), 256, 0, stream>>>(
        nullptr, features, Wc1t, projb1, q1, k1, qd1, kd1, HID_D,
        N_NODES, IN_D, 2 * HID_D);
    aggr1_k<<<(N_NODES + 3) / 4, 256, 0, stream>>>(
        offs, recs, qd1, kd1, projb1, inv1, h1b, N_NODES);

    // ---- layer 2 ----
    gemm_bf16_k<false><<<dim3(1, MB128), 256, 0, stream>>>(
        h1b, nullptr, Wc2t, projb2, q2, k2, qd2, kd2, OUT_D,
        N_NODES, HID_D, 2 * OUT_D);
    aggr2_k<<<(N_NODES + 3) / 4, 256, 0, stream>>>(
        offs, recs, qd2, kd2, projb2, inv2, out_h2, h2h, h2l, N_NODES);

    // ---- attention outputs (both layers, one pass over E) ----
    att_k<<<(N_EDGE + 255) / 256, 256, 0, stream>>>(
        srcv, dstv, etype, qd1, kd1, inv1, qd2, kd2, inv2, att1, att2,
        N_EDGE, N_NODES);

    // ---- decoder (split-bf16 MFMA, fp32-accurate) ----
    dec_gemm_k<true><<<dim3(1, MB128), 256, 0, stream>>>(
        h2h, h2l, dw1h, dw1l, db1, nullptr, hidh, hidl, N_NODES, OUT_D, HID_D);
    dec_gemm_k<false><<<dim3(2, MB128), 256, 0, stream>>>(
        hidh, hidl, dw2h, dw2l, db2, out_h3, nullptr, nullptr, N_NODES, HID_D, IN_D);
}

// Round 10
// 385.029 us; speedup vs baseline: 1.0412x; 1.0003x over previous
//
#include <hip/hip_runtime.h>
#include <hip/hip_bf16.h>

static constexpr int N_NODES = 50000;
static constexpr int N_EDGE  = 1000000;
static constexpr int IN_D    = 256;
static constexpr int HID_D   = 128;
static constexpr int OUT_D   = 64;
static constexpr int R_REL   = 2;

typedef __attribute__((ext_vector_type(8))) short short8;            // 8 bf16 = 4 VGPRs
typedef __attribute__((ext_vector_type(8))) unsigned short ushort8;  // store type
typedef __attribute__((ext_vector_type(4))) float float4v;

static __device__ __forceinline__ unsigned short f2bf(float v) {
    __hip_bfloat16 h = __float2bfloat16(v);
    return *(unsigned short*)&h;
}
static __device__ __forceinline__ float bf2f(unsigned short u) {
    union { unsigned int i; float f; } c; c.i = ((unsigned int)u) << 16; return c.f;
}
// low/high bf16 of a packed u32 -> f32 (1 VALU each: lshl / and)
static __device__ __forceinline__ float bflo(unsigned u) {
    union { unsigned i; float f; } c; c.i = u << 16; return c.f;
}
static __device__ __forceinline__ float bfhi(unsigned u) {
    union { unsigned i; float f; } c; c.i = u & 0xFFFF0000u; return c.f;
}
static __device__ __forceinline__ float u2f(unsigned u) {
    union { unsigned i; float f; } c; c.i = u; return c.f;
}
static __device__ __forceinline__ unsigned f2u(float f) {
    union { unsigned i; float f; } c; c.f = f; return c.i;
}
// accumulate 8 bf16 (one uint4) scaled by w into a[0..7]  (round-7 verified)
static __device__ __forceinline__ void acc8(float w, uint4 v, float (&a)[8]) {
    a[0] = fmaf(w, bflo(v.x), a[0]); a[1] = fmaf(w, bfhi(v.x), a[1]);
    a[2] = fmaf(w, bflo(v.y), a[2]); a[3] = fmaf(w, bfhi(v.y), a[3]);
    a[4] = fmaf(w, bflo(v.z), a[4]); a[5] = fmaf(w, bfhi(v.z), a[5]);
    a[6] = fmaf(w, bflo(v.w), a[6]); a[7] = fmaf(w, bfhi(v.w), a[7]);
}

// ---- merged prep: weight convert/split + zero-init of qd/kd and cntp --------
__global__ __launch_bounds__(256) void prep_k(
    const float* __restrict__ W1, const float* __restrict__ W2,
    const float* __restrict__ dw1, const float* __restrict__ dw2,
    unsigned short* __restrict__ Wc1t, unsigned short* __restrict__ Wc2t,
    unsigned short* __restrict__ dw1h, unsigned short* __restrict__ dw1l,
    unsigned short* __restrict__ dw2h, unsigned short* __restrict__ dw2l,
    uint4* __restrict__ zeroA, uint4* __restrict__ zeroB)
{
    int idx = blockIdx.x * 256 + threadIdx.x;
    if (idx < R_REL * HID_D * IN_D) {                       // 65536
        const int n = idx / IN_D, kk = idx % IN_D;
        const int r = n / HID_D, o = n % HID_D;
        Wc1t[(long)n * IN_D + kk] = f2bf(W1[((long)r * IN_D + kk) * HID_D + o]);
        return;
    }
    idx -= R_REL * HID_D * IN_D;
    if (idx < R_REL * OUT_D * HID_D) {                      // 16384
        const int n = idx / HID_D, kk = idx % HID_D;
        const int r = n / OUT_D, o = n % OUT_D;
        Wc2t[(long)n * HID_D + kk] = f2bf(W2[((long)r * HID_D + kk) * OUT_D + o]);
        return;
    }
    idx -= R_REL * OUT_D * HID_D;
    if (idx < HID_D * OUT_D) {                              // 8192
        const float v = dw1[idx];
        const unsigned short hi = f2bf(v);
        dw1h[idx] = hi; dw1l[idx] = f2bf(v - bf2f(hi));
        return;
    }
    idx -= HID_D * OUT_D;
    if (idx < IN_D * HID_D) {                               // 32768
        const float v = dw2[idx];
        const unsigned short hi = f2bf(v);
        dw2h[idx] = hi; dw2l[idx] = f2bf(v - bf2f(hi));
        return;
    }
    idx -= IN_D * HID_D;
    if (idx < 100000) {                                     // qd1/kd1/qd2/kd2: 400000 ints
        zeroA[idx] = make_uint4(0, 0, 0, 0);
        return;
    }
    idx -= 100000;
    if (idx < 200000) {                                     // cntp: 800000 ints
        zeroB[idx] = make_uint4(0, 0, 0, 0);
    }
}

// ---------------- bf16 MFMA GEMM: Cb[M,N] (bf16) = A[M,K] @ Bt[N,K]^T ----------
// BM=128 + TWO-DEEP spill-free register prefetch (named registers, batches A/B
// over K-steps of 32, outer loop steps 64). A batch issued at iter k is consumed
// a full outer iteration (~1600cy) later, so even the compiler's vmcnt(0) drain
// at each barrier finds the loads already landed (round-9: 1-deep gave only
// ~300cy of soak -> ~500cy exposed HBM latency per K-step, gemm stuck at 1.8x
// its HBM-service floor). K must be a multiple of 64 (all call sites are).
// CVT=true: A is fp32, converted to bf16 in registers during LDS commit.
// Fused q/k dot epilogue unchanged (round-9 verified).
template<bool CVT>
__global__ __launch_bounds__(256) void gemm_bf16_k(
    const unsigned short* __restrict__ A, const float* __restrict__ Af,
    const unsigned short* __restrict__ Bt,
    unsigned short* __restrict__ Cb,
    const float* __restrict__ qvec, const float* __restrict__ kvec,
    float* __restrict__ qdo, float* __restrict__ kdo, int Dq,
    int M, int K, int Nn)
{
    constexpr int BM = 128;
    constexpr int LDK = 40;   // 80 B rows: 16B-aligned, 2-way-only bank conflicts
    __shared__ __align__(16) unsigned short As[BM * LDK];
    __shared__ __align__(16) unsigned short Bs[128 * LDK];

    const int tid = threadIdx.x;
    const int wave = tid >> 6, lane = tid & 63;
    const int wm = (wave >> 1) * 64;
    const int wn = (wave & 1) * 64;
    const int bm = blockIdx.y * BM;
    const int bn = blockIdx.x * 128;
    const int l15 = lane & 15, quad = lane >> 4;

    const int ar0 = tid >> 2,          ach0 = (tid & 3) * 8;
    const int ar1 = (tid + 256) >> 2,  ach1 = (tid & 3) * 8;   // (tid+256)&3 == tid&3
    const long ga0 = (long)min(bm + ar0, M - 1) * K + ach0;
    const long ga1 = (long)min(bm + ar1, M - 1) * K + ach1;
    const long gb0 = (long)(bn + ar0) * K + ach0;
    const long gb1 = (long)(bn + ar1) * K + ach1;

    float4 fa0, fa1, fa2, fa3, fb0, fb1, fb2, fb3;   // CVT prefetch, 2 batches
    uint4  qa0, qa1, qc0, qc1;                       // bf16 A prefetch, 2 batches
    uint4  qb0, qb1, qd0, qd1;                       // B prefetch, 2 batches

#define GEMM_PREFA(k0) do {                                                 \
    if constexpr (CVT) {                                                    \
        fa0 = *(const float4*)&Af[ga0 + (k0)];                              \
        fa1 = *(const float4*)&Af[ga0 + (k0) + 4];                          \
        fa2 = *(const float4*)&Af[ga1 + (k0)];                              \
        fa3 = *(const float4*)&Af[ga1 + (k0) + 4];                          \
    } else {                                                                \
        qa0 = *(const uint4*)&A[ga0 + (k0)];                                \
        qa1 = *(const uint4*)&A[ga1 + (k0)];                                \
    }                                                                       \
    qb0 = *(const uint4*)&Bt[gb0 + (k0)];                                   \
    qb1 = *(const uint4*)&Bt[gb1 + (k0)];                                   \
} while (0)

#define GEMM_PREFB(k0) do {                                                 \
    if constexpr (CVT) {                                                    \
        fb0 = *(const float4*)&Af[ga0 + (k0)];                              \
        fb1 = *(const float4*)&Af[ga0 + (k0) + 4];                          \
        fb2 = *(const float4*)&Af[ga1 + (k0)];                              \
        fb3 = *(const float4*)&Af[ga1 + (k0) + 4];                          \
    } else {                                                                \
        qc0 = *(const uint4*)&A[ga0 + (k0)];                                \
        qc1 = *(const uint4*)&A[ga1 + (k0)];                                \
    }                                                                       \
    qd0 = *(const uint4*)&Bt[gb0 + (k0)];                                   \
    qd1 = *(const uint4*)&Bt[gb1 + (k0)];                                   \
} while (0)

#define GEMM_COMMITA() do {                                                 \
    if constexpr (CVT) {                                                    \
        uint4 o0, o1;                                                       \
        o0.x = (unsigned)f2bf(fa0.x) | ((unsigned)f2bf(fa0.y) << 16);       \
        o0.y = (unsigned)f2bf(fa0.z) | ((unsigned)f2bf(fa0.w) << 16);       \
        o0.z = (unsigned)f2bf(fa1.x) | ((unsigned)f2bf(fa1.y) << 16);       \
        o0.w = (unsigned)f2bf(fa1.z) | ((unsigned)f2bf(fa1.w) << 16);       \
        o1.x = (unsigned)f2bf(fa2.x) | ((unsigned)f2bf(fa2.y) << 16);       \
        o1.y = (unsigned)f2bf(fa2.z) | ((unsigned)f2bf(fa2.w) << 16);       \
        o1.z = (unsigned)f2bf(fa3.x) | ((unsigned)f2bf(fa3.y) << 16);       \
        o1.w = (unsigned)f2bf(fa3.z) | ((unsigned)f2bf(fa3.w) << 16);       \
        *(uint4*)&As[ar0 * LDK + ach0] = o0;                                \
        *(uint4*)&As[ar1 * LDK + ach1] = o1;                                \
    } else {                                                                \
        *(uint4*)&As[ar0 * LDK + ach0] = qa0;                               \
        *(uint4*)&As[ar1 * LDK + ach1] = qa1;                               \
    }                                                                       \
    *(uint4*)&Bs[ar0 * LDK + ach0] = qb0;                                   \
    *(uint4*)&Bs[ar1 * LDK + ach1] = qb1;                                   \
} while (0)

#define GEMM_COMMITB() do {                                                 \
    if constexpr (CVT) {                                                    \
        uint4 o0, o1;                                                       \
        o0.x = (unsigned)f2bf(fb0.x) | ((unsigned)f2bf(fb0.y) << 16);       \
        o0.y = (unsigned)f2bf(fb0.z) | ((unsigned)f2bf(fb0.w) << 16);       \
        o0.z = (unsigned)f2bf(fb1.x) | ((unsigned)f2bf(fb1.y) << 16);       \
        o0.w = (unsigned)f2bf(fb1.z) | ((unsigned)f2bf(fb1.w) << 16);       \
        o1.x = (unsigned)f2bf(fb2.x) | ((unsigned)f2bf(fb2.y) << 16);       \
        o1.y = (unsigned)f2bf(fb2.z) | ((unsigned)f2bf(fb2.w) << 16);       \
        o1.z = (unsigned)f2bf(fb3.x) | ((unsigned)f2bf(fb3.y) << 16);       \
        o1.w = (unsigned)f2bf(fb3.z) | ((unsigned)f2bf(fb3.w) << 16);       \
        *(uint4*)&As[ar0 * LDK + ach0] = o0;                                \
        *(uint4*)&As[ar1 * LDK + ach1] = o1;                                \
    } else {                                                                \
        *(uint4*)&As[ar0 * LDK + ach0] = qc0;                               \
        *(uint4*)&As[ar1 * LDK + ach1] = qc1;                               \
    }                                                                       \
    *(uint4*)&Bs[ar0 * LDK + ach0] = qd0;                                   \
    *(uint4*)&Bs[ar1 * LDK + ach1] = qd1;                                   \
} while (0)

#define GEMM_MFMA() do {                                                    \
    short8 bfrag[4];                                                        \
    _Pragma("unroll")                                                       \
    for (int nt = 0; nt < 4; ++nt)                                          \
        bfrag[nt] = *(const short8*)&Bs[(wn + nt * 16 + l15) * LDK + quad * 8]; \
    _Pragma("unroll")                                                       \
    for (int mt = 0; mt < 4; ++mt) {                                        \
        const short8 afrag = *(const short8*)&As[(wm + mt * 16 + l15) * LDK + quad * 8]; \
        _Pragma("unroll")                                                   \
        for (int nt = 0; nt < 4; ++nt)                                      \
            acc[mt][nt] = __builtin_amdgcn_mfma_f32_16x16x32_bf16(          \
                afrag, bfrag[nt], acc[mt][nt], 0, 0, 0);                    \
    }                                                                       \
} while (0)

    float4v acc[4][4];
#pragma unroll
    for (int i = 0; i < 4; ++i)
#pragma unroll
        for (int j = 0; j < 4; ++j) acc[i][j] = (float4v){0.f, 0.f, 0.f, 0.f};

    GEMM_PREFA(0);
    GEMM_PREFB(32);                       // K >= 64 at every call site
    for (int k0 = 0; k0 < K; k0 += 64) {
        GEMM_COMMITA();
        __syncthreads();
        if (k0 + 64 < K) GEMM_PREFA(k0 + 64);   // consumed one full iter later
        GEMM_MFMA();
        __syncthreads();
        GEMM_COMMITB();
        __syncthreads();
        if (k0 + 96 < K) GEMM_PREFB(k0 + 96);
        GEMM_MFMA();
        __syncthreads();
    }
#undef GEMM_PREFA
#undef GEMM_PREFB
#undef GEMM_COMMITA
#undef GEMM_COMMITB
#undef GEMM_MFMA

    // C/D layout: col = lane&15, row = quad*4 + reg (m89-verified)
#pragma unroll
    for (int mt = 0; mt < 4; ++mt)
#pragma unroll
        for (int nt = 0; nt < 4; ++nt) {
            const int n = bn + wn + nt * 16 + l15;
#pragma unroll
            for (int rg = 0; rg < 4; ++rg) {
                const int m = bm + wm + mt * 16 + quad * 4 + rg;
                if (m < M) Cb[(long)m * Nn + n] = f2bf(acc[mt][nt][rg]);
            }
        }

    // ---- fused q/k dot epilogue ----
    {
        const int r = (bn + wn) / Dq;               // wave-uniform relation
        const int obase = bn + wn - r * Dq + l15;   // o index for nt=0
#pragma unroll
        for (int mt = 0; mt < 4; ++mt)
#pragma unroll
            for (int rg = 0; rg < 4; ++rg) {
                float qp = 0.f, kp = 0.f;
#pragma unroll
                for (int nt = 0; nt < 4; ++nt) {
                    const float cv = acc[mt][nt][rg];
                    qp = fmaf(cv, qvec[obase + nt * 16], qp);
                    kp = fmaf(cv, kvec[obase + nt * 16], kp);
                }
                qp += __shfl_xor(qp, 1); kp += __shfl_xor(kp, 1);
                qp += __shfl_xor(qp, 2); kp += __shfl_xor(kp, 2);
                qp += __shfl_xor(qp, 4); kp += __shfl_xor(kp, 4);
                qp += __shfl_xor(qp, 8); kp += __shfl_xor(kp, 8);
                if (l15 == 0) {
                    const int m = bm + wm + mt * 16 + quad * 4 + rg;
                    if (m < M) {
                        atomicAdd(&qdo[2 * m + r], qp);
                        atomicAdd(&kdo[(long)r * M + m], kp);
                    }
                }
            }
    }
}

// -------- decoder split-bf16 MFMA GEMM: C = (Ah+Al)(Bh+Bl)^T + bias ------------
// Same two-deep named-register prefetch, 4 input streams. K multiple of 64... 
// dec1 has K=64 (single outer iteration; both batches prefetched in prologue).
template<bool SPLITOUT>
__global__ __launch_bounds__(256) void dec_gemm_k(
    const unsigned short* __restrict__ Ah, const unsigned short* __restrict__ Al,
    const unsigned short* __restrict__ Bh, const unsigned short* __restrict__ Bl,
    const float* __restrict__ bias, float* __restrict__ Cf,
    unsigned short* __restrict__ Ch, unsigned short* __restrict__ Cl,
    int M, int K, int Nn)
{
    constexpr int BM = 128;
    constexpr int LDK = 40;
    __shared__ __align__(16) unsigned short Ash[BM * LDK];
    __shared__ __align__(16) unsigned short Asl[BM * LDK];
    __shared__ __align__(16) unsigned short Bsh[128 * LDK];
    __shared__ __align__(16) unsigned short Bsl[128 * LDK];

    const int tid = threadIdx.x;
    const int wave = tid >> 6, lane = tid & 63;
    const int wm = (wave >> 1) * 64;
    const int wn = (wave & 1) * 64;
    const int bm = blockIdx.y * BM;
    const int bn = blockIdx.x * 128;
    const int l15 = lane & 15, quad = lane >> 4;

    const int ar0 = tid >> 2,          ach0 = (tid & 3) * 8;
    const int ar1 = (tid + 256) >> 2,  ach1 = (tid & 3) * 8;
    const long ga0 = (long)min(bm + ar0, M - 1) * K + ach0;
    const long ga1 = (long)min(bm + ar1, M - 1) * K + ach1;
    const long gb0 = (long)(bn + ar0) * K + ach0;
    const long gb1 = (long)(bn + ar1) * K + ach1;

    uint4 ph0, ph1, pl0, pl1, rh0, rh1, rl0, rl1;   // batch A
    uint4 ph2, ph3, pl2, pl3, rh2, rh3, rl2, rl3;   // batch B

#define DEC_PREFA(k0) do {                                  \
    ph0 = *(const uint4*)&Ah[ga0 + (k0)];                   \
    ph1 = *(const uint4*)&Ah[ga1 + (k0)];                   \
    pl0 = *(const uint4*)&Al[ga0 + (k0)];                   \
    pl1 = *(const uint4*)&Al[ga1 + (k0)];                   \
    rh0 = *(const uint4*)&Bh[gb0 + (k0)];                   \
    rh1 = *(const uint4*)&Bh[gb1 + (k0)];                   \
    rl0 = *(const uint4*)&Bl[gb0 + (k0)];                   \
    rl1 = *(const uint4*)&Bl[gb1 + (k0)];                   \
} while (0)

#define DEC_PREFB(k0) do {                                  \
    ph2 = *(const uint4*)&Ah[ga0 + (k0)];                   \
    ph3 = *(const uint4*)&Ah[ga1 + (k0)];                   \
    pl2 = *(const uint4*)&Al[ga0 + (k0)];                   \
    pl3 = *(const uint4*)&Al[ga1 + (k0)];                   \
    rh2 = *(const uint4*)&Bh[gb0 + (k0)];                   \
    rh3 = *(const uint4*)&Bh[gb1 + (k0)];                   \
    rl2 = *(const uint4*)&Bl[gb0 + (k0)];                   \
    rl3 = *(const uint4*)&Bl[gb1 + (k0)];                   \
} while (0)

#define DEC_COMMITA() do {                                  \
    *(uint4*)&Ash[ar0 * LDK + ach0] = ph0;                  \
    *(uint4*)&Ash[ar1 * LDK + ach1] = ph1;                  \
    *(uint4*)&Asl[ar0 * LDK + ach0] = pl0;                  \
    *(uint4*)&Asl[ar1 * LDK + ach1] = pl1;                  \
    *(uint4*)&Bsh[ar0 * LDK + ach0] = rh0;                  \
    *(uint4*)&Bsh[ar1 * LDK + ach1] = rh1;                  \
    *(uint4*)&Bsl[ar0 * LDK + ach0] = rl0;                  \
    *(uint4*)&Bsl[ar1 * LDK + ach1] = rl1;                  \
} while (0)

#define DEC_COMMITB() do {                                  \
    *(uint4*)&Ash[ar0 * LDK + ach0] = ph2;                  \
    *(uint4*)&Ash[ar1 * LDK + ach1] = ph3;                  \
    *(uint4*)&Asl[ar0 * LDK + ach0] = pl2;                  \
    *(uint4*)&Asl[ar1 * LDK + ach1] = pl3;                  \
    *(uint4*)&Bsh[ar0 * LDK + ach0] = rh2;                  \
    *(uint4*)&Bsh[ar1 * LDK + ach1] = rh3;                  \
    *(uint4*)&Bsl[ar0 * LDK + ach0] = rl2;                  \
    *(uint4*)&Bsl[ar1 * LDK + ach1] = rl3;                  \
} while (0)

#define DEC_MFMA() do {                                                     \
    short8 bh[4], bl[4];                                                    \
    _Pragma("unroll")                                                       \
    for (int nt = 0; nt < 4; ++nt) {                                        \
        bh[nt] = *(const short8*)&Bsh[(wn + nt * 16 + l15) * LDK + quad * 8]; \
        bl[nt] = *(const short8*)&Bsl[(wn + nt * 16 + l15) * LDK + quad * 8]; \
    }                                                                       \
    _Pragma("unroll")                                                       \
    for (int mt = 0; mt < 4; ++mt) {                                        \
        const short8 ah = *(const short8*)&Ash[(wm + mt * 16 + l15) * LDK + quad * 8]; \
        const short8 al = *(const short8*)&Asl[(wm + mt * 16 + l15) * LDK + quad * 8]; \
        _Pragma("unroll")                                                   \
        for (int nt = 0; nt < 4; ++nt) {                                    \
            acc[mt][nt] = __builtin_amdgcn_mfma_f32_16x16x32_bf16(ah, bh[nt], acc[mt][nt], 0, 0, 0); \
            acc[mt][nt] = __builtin_amdgcn_mfma_f32_16x16x32_bf16(al, bh[nt], acc[mt][nt], 0, 0, 0); \
            acc[mt][nt] = __builtin_amdgcn_mfma_f32_16x16x32_bf16(ah, bl[nt], acc[mt][nt], 0, 0, 0); \
        }                                                                   \
    }                                                                       \
} while (0)

    float4v acc[4][4];
#pragma unroll
    for (int i = 0; i < 4; ++i)
#pragma unroll
        for (int j = 0; j < 4; ++j) acc[i][j] = (float4v){0.f, 0.f, 0.f, 0.f};

    DEC_PREFA(0);
    DEC_PREFB(32);                        // K >= 64 at every call site
    for (int k0 = 0; k0 < K; k0 += 64) {
        DEC_COMMITA();
        __syncthreads();
        if (k0 + 64 < K) DEC_PREFA(k0 + 64);
        DEC_MFMA();
        __syncthreads();
        DEC_COMMITB();
        __syncthreads();
        if (k0 + 96 < K) DEC_PREFB(k0 + 96);
        DEC_MFMA();
        __syncthreads();
    }
#undef DEC_PREFA
#undef DEC_PREFB
#undef DEC_COMMITA
#undef DEC_COMMITB
#undef DEC_MFMA

#pragma unroll
    for (int mt = 0; mt < 4; ++mt)
#pragma unroll
        for (int nt = 0; nt < 4; ++nt) {
            const int n = bn + wn + nt * 16 + l15;
            const float bv = bias[n];
#pragma unroll
            for (int rg = 0; rg < 4; ++rg) {
                const int m = bm + wm + mt * 16 + quad * 4 + rg;
                if (m >= M) continue;
                const float v = acc[mt][nt][rg] + bv;
                if (SPLITOUT) {
                    const unsigned short hi = f2bf(v);
                    Ch[(long)m * Nn + n] = hi;
                    Cl[(long)m * Nn + n] = f2bf(v - bf2f(hi));
                } else {
                    Cf[(long)m * Nn + n] = v;
                }
            }
        }
}

// ---------------- CSR build (rank/scan/place — no atomic->scatter chain) -------
// rank_k atomics go to a line-padded counter array (stride 16 ints = 64B/node).
static constexpr int CPAD = 16;   // ints per counter slot (64 B)

__global__ __launch_bounds__(256) void rank_k(
    const int* __restrict__ dstv, int* __restrict__ cntp,
    int* __restrict__ rank, int E)
{
    const int e = blockIdx.x * blockDim.x + threadIdx.x;
    if (e >= E) return;
    rank[e] = atomicAdd(&cntp[dstv[e] * CPAD], 1);
}

__global__ __launch_bounds__(256) void scan1_k(
    const int* __restrict__ cntp, int* __restrict__ excl_out,
    int* __restrict__ bsum, int n)
{
    __shared__ int s[256];
    const int t = threadIdx.x;
    const int i = blockIdx.x * 256 + t;
    const int v = (i < n) ? cntp[i * CPAD] : 0;
    s[t] = v;
    __syncthreads();
    for (int off = 1; off < 256; off <<= 1) {
        const int x = (t >= off) ? s[t - off] : 0;
        __syncthreads();
        s[t] += x;
        __syncthreads();
    }
    if (i < n) excl_out[i] = s[t] - v;
    if (t == 255) bsum[blockIdx.x] = s[255];
}

// scan2 merged into scan3: every block redundantly scans the <=256 block sums
// in LDS (cheap) and picks its own exclusive prefix — saves a kernel launch.
__global__ __launch_bounds__(256) void scan23_k(
    const int* __restrict__ excl, const int* __restrict__ bsum,
    int* __restrict__ offs, int n, int total, int nb)
{
    __shared__ int s[256];
    __shared__ int base;
    const int t = threadIdx.x;
    const int v = (t < nb) ? bsum[t] : 0;
    s[t] = v;
    __syncthreads();
    for (int off = 1; off < 256; off <<= 1) {
        const int x = (t >= off) ? s[t - off] : 0;
        __syncthreads();
        s[t] += x;
        __syncthreads();
    }
    if (t == (int)blockIdx.x) base = s[t] - v;   // exclusive prefix for this block
    __syncthreads();
    const int i = blockIdx.x * 256 + t;
    if (i < n) offs[i] = excl[i] + base;
    if (i == 0) offs[n] = total;
}

// place_k: deterministic position, single 4B record write, no atomics.
// record = (etype << 16) | src   (src < 65536 since N_NODES = 50000)
__global__ __launch_bounds__(256) void place_k(
    const int* __restrict__ srcv, const int* __restrict__ dstv,
    const int* __restrict__ et, const int* __restrict__ rank,
    const int* __restrict__ offs, unsigned* __restrict__ recs, int E)
{
    const int e = blockIdx.x * blockDim.x + threadIdx.x;
    if (e >= E) return;
    const int pos = offs[dstv[e]] + rank[e];
    recs[pos] = (unsigned)((et[e] << 16) | srcv[e]);
}

// -------- layer-1 fused softmax+aggr+ELU, quarter-wave uint4 gather ------------
// Row = 128 bf16 = 256B = 16 lanes x uint4; 4 edges per load, 4 loads in flight
// covering 16 edges per burst. No attention writes here (att_k recomputes).
__global__ __launch_bounds__(256) void aggr1_k(
    const int* __restrict__ offs, const unsigned* __restrict__ recs,
    const float* __restrict__ qd, const float* __restrict__ kd,
    const unsigned short* __restrict__ projb,
    float* __restrict__ inv_out, unsigned short* __restrict__ h1b, int Nn)
{
    __shared__ uint2 sh[4][64];
    const int wid = threadIdx.x >> 6;
    const int d = blockIdx.x * 4 + wid;
    const int lane = threadIdx.x & 63;
    if (d >= Nn) return;
    const int beg = offs[d], end = offs[d + 1];
    const float2 qv = *(const float2*)&qd[2 * d];
    const char* pb = (const char*)projb;
    const int quarter = lane >> 4, l15 = lane & 15;
    const unsigned lb = (unsigned)(l15 << 4);            // 16B per lane
    uint2* shl = sh[wid];

    float exsum = 0.f;
    float a[8] = {0.f, 0.f, 0.f, 0.f, 0.f, 0.f, 0.f, 0.f};

    for (int b = beg; b < end; b += 64) {
        const int i = b + lane;
        float ex = 0.f; unsigned off = 0;
        if (i < end) {
            const unsigned rx = recs[i];
            const int s = (int)(rx & 0xFFFFu), t = (int)(rx >> 16);
            float av = (t ? qv.y : qv.x) + kd[t * Nn + s];
            av = av > 0.f ? av : 0.2f * av;
            ex = __expf(av);
            off = ((unsigned)s << 9) | ((unsigned)t << 8);  // s*512 + t*256 bytes
        }
        shl[lane] = make_uint2(f2u(ex), off);
        exsum += ex;                                     // reduced once at end

        const int cnt = min(64, end - b);
        for (int j = 0; j < cnt; j += 16) {
            const uint2 p0 = shl[j + quarter];
            const uint2 p1 = shl[j + 4 + quarter];
            const uint2 p2 = shl[j + 8 + quarter];
            const uint2 p3 = shl[j + 12 + quarter];
            const uint4 v0 = *(const uint4*)(pb + (p0.y + lb));
            const uint4 v1 = *(const uint4*)(pb + (p1.y + lb));
            const uint4 v2 = *(const uint4*)(pb + (p2.y + lb));
            const uint4 v3 = *(const uint4*)(pb + (p3.y + lb));
            acc8(u2f(p0.x), v0, a);
            acc8(u2f(p1.x), v1, a);
            acc8(u2f(p2.x), v2, a);
            acc8(u2f(p3.x), v3, a);
        }
    }
#pragma unroll
    for (int o = 32; o; o >>= 1) exsum += __shfl_xor(exsum, o);
    const float inv = 1.f / (exsum + 1e-16f);
    if (lane == 0) inv_out[d] = inv;
#pragma unroll
    for (int q = 0; q < 8; ++q) {
        a[q] += __shfl_xor(a[q], 32);
        a[q] += __shfl_xor(a[q], 16);
    }
    if (quarter == 0) {
        ushort8 st;
#pragma unroll
        for (int q = 0; q < 8; ++q) {
            const float e = a[q] * inv;
            st[q] = f2bf(e > 0.f ? e : expm1f(e));
        }
        *(ushort8*)&h1b[(long)d * 128 + (l15 << 3)] = st;   // dims l15*8..+7
    }
}

// -------- layer-2 fused, eighth-wave uint4 gather ------------------------------
// Row = 64 bf16 = 128B = 8 lanes x uint4; 8 edges per load, 4 loads in flight
// covering 32 edges per burst (avg degree 20 -> usually one burst per node).
__global__ __launch_bounds__(256) void aggr2_k(
    const int* __restrict__ offs, const unsigned* __restrict__ recs,
    const float* __restrict__ qd, const float* __restrict__ kd,
    const unsigned short* __restrict__ projb,
    float* __restrict__ inv_out, float* __restrict__ out,
    unsigned short* __restrict__ h2h, unsigned short* __restrict__ h2l, int Nn)
{
    __shared__ uint2 sh[4][64];
    const int wid = threadIdx.x >> 6;
    const int d = blockIdx.x * 4 + wid;
    const int lane = threadIdx.x & 63;
    if (d >= Nn) return;
    const int beg = offs[d], end = offs[d + 1];
    const float2 qv = *(const float2*)&qd[2 * d];
    const char* pb = (const char*)projb;
    const int eighth = lane >> 3, l7 = lane & 7;
    const unsigned lb = (unsigned)(l7 << 4);             // 16B per lane
    uint2* shl = sh[wid];

    float exsum = 0.f;
    float a[8] = {0.f, 0.f, 0.f, 0.f, 0.f, 0.f, 0.f, 0.f};

    for (int b = beg; b < end; b += 64) {
        const int i = b + lane;
        float ex = 0.f; unsigned off = 0;
        if (i < end) {
            const unsigned rx = recs[i];
            const int s = (int)(rx & 0xFFFFu), t = (int)(rx >> 16);
            float av = (t ? qv.y : qv.x) + kd[t * Nn + s];
            av = av > 0.f ? av : 0.2f * av;
            ex = __expf(av);
            off = ((unsigned)s << 8) | ((unsigned)t << 7);  // s*256 + t*128 bytes
        }
        shl[lane] = make_uint2(f2u(ex), off);
        exsum += ex;

        const int cnt = min(64, end - b);
        for (int j = 0; j < cnt; j += 32) {
            const uint2 p0 = shl[j + eighth];
            const uint2 p1 = shl[j + 8 + eighth];
            const uint2 p2 = shl[j + 16 + eighth];
            const uint2 p3 = shl[j + 24 + eighth];
            const uint4 v0 = *(const uint4*)(pb + (p0.y + lb));
            const uint4 v1 = *(const uint4*)(pb + (p1.y + lb));
            const uint4 v2 = *(const uint4*)(pb + (p2.y + lb));
            const uint4 v3 = *(const uint4*)(pb + (p3.y + lb));
            acc8(u2f(p0.x), v0, a);
            acc8(u2f(p1.x), v1, a);
            acc8(u2f(p2.x), v2, a);
            acc8(u2f(p3.x), v3, a);
        }
    }
#pragma unroll
    for (int o = 32; o; o >>= 1) exsum += __shfl_xor(exsum, o);
    const float inv = 1.f / (exsum + 1e-16f);
    if (lane == 0) inv_out[d] = inv;
#pragma unroll
    for (int q = 0; q < 8; ++q) {
        a[q] += __shfl_xor(a[q], 32);
        a[q] += __shfl_xor(a[q], 16);
        a[q] += __shfl_xor(a[q], 8);
    }
    if (eighth == 0) {
        float vv[8];
#pragma unroll
        for (int q = 0; q < 8; ++q) {
            const float e = a[q] * inv;
            vv[q] = e > 0.f ? e : expm1f(e);
        }
        float4 f0; f0.x = vv[0]; f0.y = vv[1]; f0.z = vv[2]; f0.w = vv[3];
        float4 f1; f1.x = vv[4]; f1.y = vv[5]; f1.z = vv[6]; f1.w = vv[7];
        *(float4*)&out[(long)d * 64 + (l7 << 3)] = f0;
        *(float4*)&out[(long)d * 64 + (l7 << 3) + 4] = f1;
        ushort8 hh, hl;
#pragma unroll
        for (int q = 0; q < 8; ++q) {
            const unsigned short hi = f2bf(vv[q]);
            hh[q] = hi; hl[q] = f2bf(vv[q] - bf2f(hi));
        }
        *(ushort8*)&h2h[(long)d * 64 + (l7 << 3)] = hh;
        *(ushort8*)&h2l[(long)d * 64 + (l7 << 3)] = hl;
    }
}

// -------- attention outputs: recompute alpha for both layers, one edge pass ----
// Identical FP expressions/inputs as the aggr kernels -> consistent softmax.
__global__ __launch_bounds__(256) void att_k(
    const int* __restrict__ srcv, const int* __restrict__ dstv,
    const int* __restrict__ et,
    const float* __restrict__ qd1, const float* __restrict__ kd1,
    const float* __restrict__ inv1,
    const float* __restrict__ qd2, const float* __restrict__ kd2,
    const float* __restrict__ inv2,
    float* __restrict__ att1, float* __restrict__ att2, int E, int Nn)
{
    const int e = blockIdx.x * 256 + threadIdx.x;
    if (e >= E) return;
    const int s = srcv[e], d = dstv[e], t = et[e];
    float x1 = qd1[2 * d + t] + kd1[t * Nn + s];
    x1 = x1 > 0.f ? x1 : 0.2f * x1;
    att1[e] = __expf(x1) * inv1[d];
    float x2 = qd2[2 * d + t] + kd2[t * Nn + s];
    x2 = x2 > 0.f ? x2 : 0.2f * x2;
    att2[e] = __expf(x2) * inv2[d];
}

extern "C" void kernel_launch(void* const* d_in, const int* in_sizes, int n_in,
                              void* d_out, int out_size, void* d_ws, size_t ws_size,
                              hipStream_t stream)
{
    const float* features = (const float*)d_in[0];
    const int*   eidx     = (const int*)d_in[1];
    const int*   etype    = (const int*)d_in[2];
    const float* W1       = (const float*)d_in[3];
    const float* q1       = (const float*)d_in[4];
    const float* k1       = (const float*)d_in[5];
    const float* W2       = (const float*)d_in[6];
    const float* q2       = (const float*)d_in[7];
    const float* k2       = (const float*)d_in[8];
    const float* dw1      = (const float*)d_in[9];
    const float* db1      = (const float*)d_in[10];
    const float* dw2      = (const float*)d_in[11];
    const float* db2      = (const float*)d_in[12];

    const int* srcv = eidx;
    const int* dstv = eidx + N_EDGE;

    float* out_h2 = (float*)d_out;                  // N x 64
    float* out_h3 = out_h2 + (long)N_NODES * OUT_D; // N x 256
    float* att1   = out_h3 + (long)N_NODES * IN_D;  // E
    float* att2   = att1 + N_EDGE;                  // E

    // ---- workspace carve-up ----
    // Liveness: rank aliases projb1's first 4 MB — rank dies at place_k, and
    // projb1 is first written by gemm_bf16_k which launches AFTER place_k.
    // cntp (line-padded counters, 3.2MB at [53.9M, 57.1M)) dies at scan1;
    // inv1/inv2 live at [53.5M, 53.9M), no overlap. recs starts at 57.3M.
    // qd/kd (contiguous [51.2M, 52.8M)) are zeroed by prep_k and filled by
    // the gemm dot-epilogue atomics.
    char* W = (char*)d_ws;
    int* rank = (int*)W;                                       // [0, 4M)  (aliases projb1)
    unsigned short* projb1 = (unsigned short*)(W);             // [0, 25.6M)
    unsigned short* projb2 = (unsigned short*)(W);             // alias
    unsigned short* hidh   = (unsigned short*)(W);             // [0, 12.8M) after aggr2
    unsigned short* hidl   = (unsigned short*)(W + 12800000);
    unsigned short* h1b    = (unsigned short*)(W + 25600000);  // [25.6M, 38.4M)
    unsigned short* h2h    = (unsigned short*)(W + 25600000 + 12800000);
    unsigned short* h2l    = (unsigned short*)(W + 25600000 + 19200000);
    float* qd1 = (float*)(W + 51200000);            // interleaved [node][2]
    float* kd1 = qd1 + 2 * N_NODES;
    float* qd2 = kd1 + 2 * N_NODES;
    float* kd2 = qd2 + 2 * N_NODES;
    int* offs   = (int*)(kd2 + 2 * N_NODES);        // [52.8M, 53.0M)
    int* bsum   = offs + N_NODES + 1;
    int* bpre   = bsum + 256;                       // (unused slot kept for layout)
    int* excl   = bpre + 256;                       // ends ~53.2M
    float* inv1 = (float*)(W + 53500000);           // [53.5M, 53.7M)
    float* inv2 = inv1 + N_NODES;                   // [53.7M, 53.9M)
    int* cntp   = (int*)(W + 53900000);             // [53.9M, 57.1M) padded counters
    unsigned* recs = (unsigned*)(W + 57300000);     // [57.3M, 61.3M)
    unsigned short* Wc1t = (unsigned short*)(W + 65300000);    // 65536 us
    unsigned short* Wc2t = Wc1t + 65536;                       // 16384 us
    unsigned short* dw1h = Wc2t + 16384;                       // 8192
    unsigned short* dw1l = dw1h + 8192;
    unsigned short* dw2h = dw1l + 8192;                        // 32768
    unsigned short* dw2l = dw2h + 32768;

    const int NB = (N_NODES + 255) / 256;
    const int MB128 = (N_NODES + 127) / 128;        // 391 row-tiles at BM=128

    // ---- prep: weight conversions + zero-init (qd/kd, cntp) in one kernel ----
    prep_k<<<1652, 256, 0, stream>>>(W1, W2, dw1, dw2,
                                     Wc1t, Wc2t, dw1h, dw1l, dw2h, dw2l,
                                     (uint4*)qd1, (uint4*)cntp);

    rank_k<<<(N_EDGE + 255) / 256, 256, 0, stream>>>(dstv, cntp, rank, N_EDGE);
    scan1_k<<<NB, 256, 0, stream>>>(cntp, excl, bsum, N_NODES);
    scan23_k<<<NB, 256, 0, stream>>>(excl, bsum, offs, N_NODES, N_EDGE, NB);
    place_k<<<(N_EDGE + 255) / 256, 256, 0, stream>>>(
        srcv, dstv, etype, rank, offs, recs, N_EDGE);

    // ---- layer 1 (fp32->bf16 fused staging + fused q/k dot epilogue) ----
    gemm_bf16_k<true><<<dim3(2, MB128), 256, 0, stream>>>(
        nullptr, features, Wc1t, projb1, q1, k1, qd1, kd1, HID_D,
        N_NODES, IN_D, 2 * HID_D);
    aggr1_k<<<(N_NODES + 3) / 4, 256, 0, stream>>>(
        offs, recs, qd1, kd1, projb1, inv1, h1b, N_NODES);

    // ---- layer 2 ----
    gemm_bf16_k<false><<<dim3(1, MB128), 256, 0, stream>>>(
        h1b, nullptr, Wc2t, projb2, q2, k2, qd2, kd2, OUT_D,
        N_NODES, HID_D, 2 * OUT_D);
    aggr2_k<<<(N_NODES + 3) / 4, 256, 0, stream>>>(
        offs, recs, qd2, kd2, projb2, inv2, out_h2, h2h, h2l, N_NODES);

    // ---- attention outputs (both layers, one pass over E) ----
    att_k<<<(N_EDGE + 255) / 256, 256, 0, stream>>>(
        srcv, dstv, etype, qd1, kd1, inv1, qd2, kd2, inv2, att1, att2,
        N_EDGE, N_NODES);

    // ---- decoder (split-bf16 MFMA, fp32-accurate) ----
    dec_gemm_k<true><<<dim3(1, MB128), 256, 0, stream>>>(
        h2h, h2l, dw1h, dw1l, db1, nullptr, hidh, hidl, N_NODES, OUT_D, HID_D);
    dec_gemm_k<false><<<dim3(2, MB128), 256, 0, stream>>>(
        hidh, hidl, dw2h, dw2l, db2, out_h3, nullptr, nullptr, N_NODES, HID_D, IN_D);
}